// Round 4
// baseline (276.811 us; speedup 1.0000x reference)
//
#include <hip/hip_runtime.h>
#include <hip/hip_bf16.h>
#include <math.h>

// Problem constants (B=1)
#define T_DIM 2048
#define D_DIM 2048
#define N_HEADS 16
#define K_HEADS 8
#define H_DIM 128
#define WINDOW_SZ 1024
#define SOFT_CAP 50.0f
#define Q_SCALE 0.08838834764831845f   // 1/sqrt(128)
#define LN_BASE 9.210340371976184f     // ln(10000)

typedef __hip_bfloat16 bf16;
typedef __attribute__((ext_vector_type(8))) short short8;
typedef __attribute__((ext_vector_type(4))) float floatx4;

static __device__ __forceinline__ bf16 f2b(float v) { return __float2bfloat16(v); }
static __device__ __forceinline__ float b2f(bf16 v) { return __bfloat162float(v); }

// ---------------------------------------------------------------------------
// Fused prep: 1D grid.
//   [0, 8192)     : qkv weight transpose (32 matrices, 2048x128 -> rows z*128 of WT_qkv)
//   [8192, 12288) : out weight transpose (16 matrices, 128x2048 -> cols z*128 of WT_out)
//   [12288,14336) : x fp32 -> bf16 copy
// ---------------------------------------------------------------------------
__global__ __launch_bounds__(256) void prep_k(
    const float* __restrict__ x, const float* __restrict__ qk,
    const float* __restrict__ kvk, const float* __restrict__ ok,
    bf16* __restrict__ xb, bf16* __restrict__ WT_qkv, bf16* __restrict__ WT_out)
{
    __shared__ float tile[32][33];
    const int b = blockIdx.x;
    const int tid = threadIdx.x;
    const int tx = tid & 31, ty = tid >> 5;

    if (b < 8192) {
        const int z = b >> 8, rem = b & 255;
        const int c0 = (rem & 3) * 32;        // over H (128)
        const int r0 = (rem >> 2) * 32;       // over D (2048)
        const float* src = (z < 16) ? qk + (size_t)z * D_DIM * H_DIM
                                    : kvk + (size_t)(z - 16) * D_DIM * H_DIM;
        bf16* dst = WT_qkv + (size_t)z * 128 * 2048;
#pragma unroll
        for (int i = 0; i < 4; ++i)
            tile[ty + i * 8][tx] = src[(size_t)(r0 + ty + i * 8) * H_DIM + c0 + tx];
        __syncthreads();
#pragma unroll
        for (int i = 0; i < 4; ++i)
            dst[(size_t)(c0 + ty + i * 8) * 2048 + r0 + tx] = f2b(tile[tx][ty + i * 8]);
    } else if (b < 12288) {
        const int b2 = b - 8192;
        const int z = b2 >> 8, rem = b2 & 255;
        const int c0 = (rem & 63) * 32;       // over D (2048)
        const int r0 = (rem >> 6) * 32;       // over H (128)
        const float* src = ok + (size_t)z * H_DIM * D_DIM;
        bf16* dst = WT_out + (size_t)z * H_DIM;
#pragma unroll
        for (int i = 0; i < 4; ++i)
            tile[ty + i * 8][tx] = src[(size_t)(r0 + ty + i * 8) * D_DIM + c0 + tx];
        __syncthreads();
#pragma unroll
        for (int i = 0; i < 4; ++i)
            dst[(size_t)(c0 + ty + i * 8) * 2048 + r0 + tx] = f2b(tile[tx][ty + i * 8]);
    } else {
        const size_t i = ((size_t)(b - 12288) * 256 + tid) * 8;
        float4 a = *(const float4*)(x + i);
        float4 bb = *(const float4*)(x + i + 4);
        bf16 o[8] = {f2b(a.x), f2b(a.y), f2b(a.z), f2b(a.w),
                     f2b(bb.x), f2b(bb.y), f2b(bb.z), f2b(bb.w)};
        *(short8*)(xb + i) = *(const short8*)o;
    }
}

// ---------------------------------------------------------------------------
// 256x256 8-phase GEMM (T2+T3+T4+T5), QKV projection, SPLIT-K z=2 (round-1).
// ---------------------------------------------------------------------------
static __device__ __forceinline__ void stageT(const bf16* __restrict__ gsrc,
                                              bf16* ldst, int h, int r, int kt)
{
    __builtin_amdgcn_global_load_lds(
        (const __attribute__((address_space(1))) void*)
            (gsrc + (size_t)((h * 128 + r * 64) * 2048 + kt * 64)),
        (__attribute__((address_space(3))) void*)(ldst + h * 8192 + r * 4096),
        16, 0, 0);
}

template <int MTB>
static __device__ __forceinline__ void readA4(short8 (&dst)[4][2], const bf16* base,
                                              int rlo, const int (&cs)[2])
{
#pragma unroll
    for (int mt = 0; mt < 4; ++mt)
#pragma unroll
        for (int ks = 0; ks < 2; ++ks)
            dst[mt][ks] = *(const short8*)&base[(rlo + (MTB + mt) * 16) * 64 + cs[ks]];
}

template <int NTB>
static __device__ __forceinline__ void readB2(short8 (&dst)[2][2], const bf16* base,
                                              int rlo, const int (&cs)[2])
{
#pragma unroll
    for (int n2 = 0; n2 < 2; ++n2)
#pragma unroll
        for (int ks = 0; ks < 2; ++ks)
            dst[n2][ks] = *(const short8*)&base[(rlo + (NTB + n2) * 16) * 64 + cs[ks]];
}

template <int MB, int NB>
static __device__ __forceinline__ void mfma16(floatx4 (&acc)[8][4],
                                              const short8 (&af)[4][2],
                                              const short8 (&bf)[2][2])
{
#pragma unroll
    for (int mt = 0; mt < 4; ++mt)
#pragma unroll
        for (int n2 = 0; n2 < 2; ++n2) {
            acc[MB + mt][NB + n2] = __builtin_amdgcn_mfma_f32_16x16x32_bf16(
                af[mt][0], bf[n2][0], acc[MB + mt][NB + n2], 0, 0, 0);
            acc[MB + mt][NB + n2] = __builtin_amdgcn_mfma_f32_16x16x32_bf16(
                af[mt][1], bf[n2][1], acc[MB + mt][NB + n2], 0, 0, 0);
        }
}

__global__ __launch_bounds__(512, 2) void gemm_qkv_8ph_k(
    const bf16* __restrict__ A, const bf16* __restrict__ BT,
    bf16* __restrict__ P0, bf16* __restrict__ P1)
{
    __shared__ alignas(16) bf16 lds[2][2][16384];   // [buf][A/B][256*64]

    const int tid  = threadIdx.x;
    const int lane = tid & 63;
    const int wave = tid >> 6;
    const int lo   = lane & 15;
    const int quad = lane >> 4;

    const int wg   = blockIdx.x;
    const int row0 = (wg & 7) * 256;
    const int col0 = (wg >> 3) * 256;
    const int kb   = blockIdx.y * 16;            // K-tile base (z * 1024 elems)
    bf16* __restrict__ Pd = blockIdx.y ? P1 : P0;

    const int wm   = (wave >> 2) * 128;   // WARPS_M = 2
    const int wn   = (wave & 3) * 64;     // WARPS_N = 4
    const int wmlo = wm + lo, wnlo = wn + lo;

    const int r_y   = wave * 8 + (lane >> 3);                   // 0..63
    const int c_src = ((lane & 7) ^ ((lane >> 3) & 7)) * 8;     // elements
    const bf16* pA = A  + (size_t)(row0 + r_y) * 2048 + c_src;
    const bf16* pB = BT + (size_t)(col0 + r_y) * 2048 + c_src;

    bf16* ldsA0 = &lds[0][0][0] + wave * 512;
    bf16* ldsB0 = &lds[0][1][0] + wave * 512;
    bf16* ldsA1 = &lds[1][0][0] + wave * 512;
    bf16* ldsB1 = &lds[1][1][0] + wave * 512;

    const int cs[2] = { (quad * 8) ^ ((lo & 7) << 3),
                        (32 + quad * 8) ^ ((lo & 7) << 3) };

    floatx4 acc[8][4];
#pragma unroll
    for (int i = 0; i < 8; ++i)
#pragma unroll
        for (int j = 0; j < 4; ++j) acc[i][j] = (floatx4){0.f, 0.f, 0.f, 0.f};

    stageT(pA, ldsA0, 0, 0, kb); stageT(pA, ldsA0, 0, 1, kb);
    stageT(pA, ldsA0, 1, 0, kb); stageT(pA, ldsA0, 1, 1, kb);
    stageT(pB, ldsB0, 0, 0, kb); stageT(pB, ldsB0, 0, 1, kb);
    stageT(pB, ldsB0, 1, 0, kb); stageT(pB, ldsB0, 1, 1, kb);
    stageT(pA, ldsA1, 0, 0, kb + 1); stageT(pA, ldsA1, 0, 1, kb + 1);
    stageT(pA, ldsA1, 1, 0, kb + 1); stageT(pA, ldsA1, 1, 1, kb + 1);
    stageT(pB, ldsB1, 0, 0, kb + 1); stageT(pB, ldsB1, 0, 1, kb + 1);
    asm volatile("s_waitcnt vmcnt(6)" ::: "memory");   // tile kb fully landed
    __builtin_amdgcn_s_barrier();

    short8 aF[4][2], a2F[4][2], bF[2][2], b2F[2][2];

#pragma unroll 1
    for (int i = 0; i < 8; ++i) {
        const int tb1  = kb + 2 * i + 1;
        const int lt0  = (2 * i + 2 < 16) ? 2 * i + 2 : 15;
        const int lt1  = (2 * i + 3 < 16) ? 2 * i + 3 : 15;
        const int tnx0 = kb + lt0;
        const int tnx1 = kb + lt1;

        // ======== group 0: compute K-tile kb+2i from buf0 ========
        readA4<0>(aF, &lds[0][0][0], wmlo, cs);
        readB2<0>(bF, &lds[0][1][0], wnlo, cs);
        stageT(pB, ldsB1, 1, 0, tb1); stageT(pB, ldsB1, 1, 1, tb1);
        __builtin_amdgcn_s_barrier();
        __builtin_amdgcn_s_setprio(1); mfma16<0, 0>(acc, aF, bF);   __builtin_amdgcn_s_setprio(0);
        __builtin_amdgcn_s_barrier();
        readA4<4>(a2F, &lds[0][0][0], wmlo, cs);
        readB2<2>(b2F, &lds[0][1][0], wnlo, cs);
        __builtin_amdgcn_s_barrier();
        __builtin_amdgcn_s_setprio(1); mfma16<4, 2>(acc, a2F, b2F); __builtin_amdgcn_s_setprio(0);
        __builtin_amdgcn_s_barrier();
        stageT(pA, ldsA0, 0, 0, tnx0); stageT(pA, ldsA0, 0, 1, tnx0);
        stageT(pA, ldsA0, 1, 0, tnx0); stageT(pA, ldsA0, 1, 1, tnx0);
        __builtin_amdgcn_s_barrier();
        __builtin_amdgcn_s_setprio(1); mfma16<0, 2>(acc, aF, b2F);  __builtin_amdgcn_s_setprio(0);
        __builtin_amdgcn_s_barrier();
        stageT(pB, ldsB0, 0, 0, tnx0); stageT(pB, ldsB0, 0, 1, tnx0);
        asm volatile("s_waitcnt vmcnt(6)" ::: "memory");
        __builtin_amdgcn_s_barrier();
        __builtin_amdgcn_s_setprio(1); mfma16<4, 0>(acc, a2F, bF);  __builtin_amdgcn_s_setprio(0);
        __builtin_amdgcn_s_barrier();

        // ======== group 1: compute K-tile kb+2i+1 from buf1 ========
        readA4<0>(aF, &lds[1][0][0], wmlo, cs);
        readB2<0>(bF, &lds[1][1][0], wnlo, cs);
        stageT(pB, ldsB0, 1, 0, tnx0); stageT(pB, ldsB0, 1, 1, tnx0);
        __builtin_amdgcn_s_barrier();
        __builtin_amdgcn_s_setprio(1); mfma16<0, 0>(acc, aF, bF);   __builtin_amdgcn_s_setprio(0);
        __builtin_amdgcn_s_barrier();
        readA4<4>(a2F, &lds[1][0][0], wmlo, cs);
        readB2<2>(b2F, &lds[1][1][0], wnlo, cs);
        __builtin_amdgcn_s_barrier();
        __builtin_amdgcn_s_setprio(1); mfma16<4, 2>(acc, a2F, b2F); __builtin_amdgcn_s_setprio(0);
        __builtin_amdgcn_s_barrier();
        stageT(pA, ldsA1, 0, 0, tnx1); stageT(pA, ldsA1, 0, 1, tnx1);
        stageT(pA, ldsA1, 1, 0, tnx1); stageT(pA, ldsA1, 1, 1, tnx1);
        __builtin_amdgcn_s_barrier();
        __builtin_amdgcn_s_setprio(1); mfma16<0, 2>(acc, aF, b2F);  __builtin_amdgcn_s_setprio(0);
        __builtin_amdgcn_s_barrier();
        stageT(pB, ldsB1, 0, 0, tnx1); stageT(pB, ldsB1, 0, 1, tnx1);
        asm volatile("s_waitcnt vmcnt(6)" ::: "memory");
        __builtin_amdgcn_s_barrier();
        __builtin_amdgcn_s_setprio(1); mfma16<4, 0>(acc, a2F, bF);  __builtin_amdgcn_s_setprio(0);
        __builtin_amdgcn_s_barrier();
    }

#pragma unroll
    for (int mt = 0; mt < 8; ++mt)
#pragma unroll
        for (int nt = 0; nt < 4; ++nt)
#pragma unroll
            for (int r = 0; r < 4; ++r) {
                int rr = row0 + wm + mt * 16 + quad * 4 + r;
                int cc = col0 + wn + nt * 16 + lo;
                Pd[(size_t)rr * 4096 + cc] = f2b(acc[mt][nt][r]);
            }
}

// ---------------------------------------------------------------------------
// qkvb += P0 (bf16 partial combine, short8-vectorized)
// ---------------------------------------------------------------------------
__global__ __launch_bounds__(256) void qkv_add_k(
    const bf16* __restrict__ P0, bf16* __restrict__ qkvb)
{
    const size_t i = ((size_t)blockIdx.x * 256 + threadIdx.x) * 8;
    short8 a = *(const short8*)(P0 + i);
    short8 b = *(const short8*)(qkvb + i);
    const bf16* ap = (const bf16*)&a;
    const bf16* bp = (const bf16*)&b;
    bf16 o[8];
#pragma unroll
    for (int j = 0; j < 8; ++j) o[j] = f2b(b2f(ap[j]) + b2f(bp[j]));
    *(short8*)(qkvb + i) = *(const short8*)o;
}

// ---------------------------------------------------------------------------
// Split-K MFMA GEMM: grid.z selects K-half; writes fp32 partials.
// 128x128 tile (m97 structure); Ndim=2048, K-half = 1024.
// ---------------------------------------------------------------------------
__global__ __launch_bounds__(256) void mfma_gemm_splitk_k(
    const bf16* __restrict__ A, const bf16* __restrict__ BT,
    float* __restrict__ P0, float* __restrict__ P1)
{
    __shared__ alignas(16) bf16 As[128 * 32];
    __shared__ alignas(16) bf16 Bs[128 * 32];

    const int tid  = threadIdx.x;
    const int lane = tid & 63;
    const int wave = tid >> 6;
    const int lo   = lane & 15;
    const int quad = lane >> 4;
    const int row0 = blockIdx.x * 128;
    const int col0 = blockIdx.y * 128;
    const int kbeg = blockIdx.z * 1024;
    float* __restrict__ P = blockIdx.z ? P1 : P0;
    const int wm = (wave >> 1) * 64;
    const int wn = (wave & 1) * 64;

    const int lrow = lane >> 2;
    const int lcol = ((lane & 3) ^ ((lane >> 3) & 3)) * 8;
    const int swk  = (quad ^ ((lo >> 1) & 3)) * 8;

    floatx4 acc[4][4];
#pragma unroll
    for (int i = 0; i < 4; ++i)
#pragma unroll
        for (int j = 0; j < 4; ++j) acc[i][j] = (floatx4){0.f, 0.f, 0.f, 0.f};

    for (int k0 = kbeg; k0 < kbeg + 1024; k0 += 32) {
        __syncthreads();
#pragma unroll
        for (int i = 0; i < 2; ++i) {
            const int trow = wave * 32 + i * 16 + lrow;
            const bf16* ga = A  + (size_t)(row0 + trow) * 2048 + k0 + lcol;
            const bf16* gb = BT + (size_t)(col0 + trow) * 2048 + k0 + lcol;
            __builtin_amdgcn_global_load_lds(
                (const __attribute__((address_space(1))) void*)ga,
                (__attribute__((address_space(3))) void*)(As + (wave * 2 + i) * 512),
                16, 0, 0);
            __builtin_amdgcn_global_load_lds(
                (const __attribute__((address_space(1))) void*)gb,
                (__attribute__((address_space(3))) void*)(Bs + (wave * 2 + i) * 512),
                16, 0, 0);
        }
        __syncthreads();

        short8 af[4], bfr[4];
#pragma unroll
        for (int mt = 0; mt < 4; ++mt)
            af[mt] = *(const short8*)&As[(wm + mt * 16 + lo) * 32 + swk];
#pragma unroll
        for (int nt = 0; nt < 4; ++nt)
            bfr[nt] = *(const short8*)&Bs[(wn + nt * 16 + lo) * 32 + swk];
#pragma unroll
        for (int mt = 0; mt < 4; ++mt)
#pragma unroll
            for (int nt = 0; nt < 4; ++nt)
                acc[mt][nt] = __builtin_amdgcn_mfma_f32_16x16x32_bf16(
                    af[mt], bfr[nt], acc[mt][nt], 0, 0, 0);
    }

#pragma unroll
    for (int mt = 0; mt < 4; ++mt)
#pragma unroll
        for (int nt = 0; nt < 4; ++nt)
#pragma unroll
            for (int r = 0; r < 4; ++r) {
                int rr = row0 + wm + mt * 16 + quad * 4 + r;
                int cc = col0 + wn + nt * 16 + lo;
                P[(size_t)rr * 2048 + cc] = acc[mt][nt][r];
            }
}

// ---------------------------------------------------------------------------
// out = P0 + P1 (float4, 4 elems/thread)
// ---------------------------------------------------------------------------
__global__ __launch_bounds__(256) void add_out_k(
    const float* __restrict__ P0, const float* __restrict__ P1,
    float* __restrict__ out)
{
    const size_t i = ((size_t)blockIdx.x * 256 + threadIdx.x) * 4;
    float4 a = *(const float4*)(P0 + i);
    float4 b = *(const float4*)(P1 + i);
    float4 o = {a.x + b.x, a.y + b.y, a.z + b.z, a.w + b.w};
    *(float4*)(out + i) = o;
}

// ---------------------------------------------------------------------------
// RoPE on K only (q-rope fused into attn). 512 pairs per t.
// ---------------------------------------------------------------------------
__global__ __launch_bounds__(256) void rope_kk(bf16* __restrict__ qkvb,
                                               const int* __restrict__ segpos)
{
    const int t = blockIdx.x;
    const float pos = (float)segpos[t];
    bf16* rowp = qkvb + (size_t)t * 4096 + 2048;
#pragma unroll
    for (int it = 0; it < 2; ++it) {
        int p = threadIdx.x + it * 256;
        int hp = p & 63;
        bf16* buf = rowp + (p >> 6) * 128;
        float fraction = (float)hp * (1.0f / 64.0f);
        float inv_ts = __expf(-fraction * LN_BASE);
        float ang = pos * inv_ts;
        float sv, cv; __sincosf(ang, &sv, &cv);
        float first  = b2f(buf[hp]);
        float second = b2f(buf[hp + 64]);
        buf[hp]      = f2b(first * cv - second * sv);
        buf[hp + 64] = f2b(second * cv + first * sv);
    }
}

// ---------------------------------------------------------------------------
// Flash MFMA attention, fixed-m softmax (softcap bounds logits to ±50).
// Round-2 restructure: 32-row Q-blocks, key-parity split across wave pairs.
//   waves 0,1: rows [0,16)/[16,32), even chunks (buf 0)
//   waves 2,3: same rows, odd chunks (buf 1)
// Fixed-m softmax is linear -> partials combine by addition via LDS.
// Grid (64,16) = 1024 blocks, bx rotated per head for CU load balance;
// LDS 43008 -> 3 blocks/CU resident (12 waves/CU, was 8).
// ---------------------------------------------------------------------------
union AttnSmem {
    struct {
        bf16 Ks[2][32][136];
        bf16 Vt[2][128][40];
        bf16 Ps[4][16][40];
    } a;
    struct {              // post-loop combine area (overlaps Ks/Vt only)
        float L[2][4][64];
        float O[2][8][4][64];
    } b;
};

__global__ __launch_bounds__(256) void attn_k(
    const bf16* __restrict__ qkvb, const int* __restrict__ segpos,
    bf16* __restrict__ ebuf)
{
    __shared__ alignas(16) AttnSmem sm;

    const int n   = blockIdx.y;
    const int bx  = (int)((blockIdx.x + 17u * n) & 63u);   // balance rotation
    const int t0  = bx * 32;
    const int kh  = n >> 1;
    const int tid  = threadIdx.x;
    const int lane = tid & 63;
    const int wave = tid >> 6;        // 0..3
    const int lo   = lane & 15;
    const int quad = lane >> 4;
    const int par  = wave >> 1;       // 0: even chunks, 1: odd chunks
    const int trow0 = t0 + (wave & 1) * 16;   // this wave's 16 query rows

    short8 qf[4];
    {
        const int tq = trow0 + lo;
        const float pos = (float)segpos[tq];
        const bf16* qp = qkvb + (size_t)tq * 4096 + n * 128;
        float qv[4][8];
#pragma unroll
        for (int kc = 0; kc < 4; ++kc) {
            short8 raw = *(const short8*)(qp + kc * 32 + quad * 8);
            const bf16* rb = (const bf16*)&raw;
#pragma unroll
            for (int j = 0; j < 8; ++j) qv[kc][j] = b2f(rb[j]);
        }
#pragma unroll
        for (int kc = 0; kc < 2; ++kc)
#pragma unroll
            for (int j = 0; j < 8; ++j) {
                int hp = kc * 32 + quad * 8 + j;
                float ang = pos * __expf(-(float)hp * (1.0f / 64.0f) * LN_BASE);
                float sv, cv; __sincosf(ang, &sv, &cv);
                float first = qv[kc][j], second = qv[kc + 2][j];
                qv[kc][j]     = (first * cv - second * sv) * Q_SCALE;
                qv[kc + 2][j] = (second * cv + first * sv) * Q_SCALE;
            }
#pragma unroll
        for (int kc = 0; kc < 4; ++kc) {
            bf16 o[8];
#pragma unroll
            for (int j = 0; j < 8; ++j) o[j] = f2b(qv[kc][j]);
            qf[kc] = *(const short8*)o;
        }
    }

    floatx4 O[8];
#pragma unroll
    for (int i = 0; i < 8; ++i) O[i] = (floatx4){0.f, 0.f, 0.f, 0.f};
    float l_acc[4] = {0.f, 0.f, 0.f, 0.f};

    const int key_a = tid >> 3,      hd_a = (tid & 7) * 16;
    const int kp2   = (tid & 15) * 2, hd_b = (tid >> 4) * 8;

    const int s_start = (t0 >= 1024) ? (t0 - 1024) : 0;
    const int nch     = (t0 + 31 - s_start) / 32 + 1;
    const int npairs  = (nch + 1) >> 1;

    const bf16* kg = qkvb + 2048 + kh * 128;
    const bf16* vg = qkvb + 3072 + kh * 128;

    // preload pair 0 (odd-chunk base clamped; compute guards validity)
    int b0 = s_start;
    int b1 = (s_start + 32 > 2016) ? 2016 : (s_start + 32);
    short8 kr0 = *(const short8*)(kg + (size_t)(b0 + key_a) * 4096 + hd_a);
    short8 kr1 = *(const short8*)(kg + (size_t)(b0 + key_a) * 4096 + hd_a + 8);
    short8 vr0 = *(const short8*)(vg + (size_t)(b0 + kp2) * 4096 + hd_b);
    short8 vr1 = *(const short8*)(vg + (size_t)(b0 + kp2 + 1) * 4096 + hd_b);
    short8 kr2 = *(const short8*)(kg + (size_t)(b1 + key_a) * 4096 + hd_a);
    short8 kr3 = *(const short8*)(kg + (size_t)(b1 + key_a) * 4096 + hd_a + 8);
    short8 vr2 = *(const short8*)(vg + (size_t)(b1 + kp2) * 4096 + hd_b);
    short8 vr3 = *(const short8*)(vg + (size_t)(b1 + kp2 + 1) * 4096 + hd_b);

    for (int p = 0; p < npairs; ++p) {
        // stage both parity buffers
        *(short8*)&sm.a.Ks[0][key_a][hd_a]     = kr0;
        *(short8*)&sm.a.Ks[0][key_a][hd_a + 8] = kr1;
        *(short8*)&sm.a.Ks[1][key_a][hd_a]     = kr2;
        *(short8*)&sm.a.Ks[1][key_a][hd_a + 8] = kr3;
#pragma unroll
        for (int i = 0; i < 8; ++i) {
            unsigned pk0 = (unsigned)(unsigned short)vr0[i] |
                           ((unsigned)(unsigned short)vr1[i] << 16);
            unsigned pk1 = (unsigned)(unsigned short)vr2[i] |
                           ((unsigned)(unsigned short)vr3[i] << 16);
            *(unsigned*)&sm.a.Vt[0][hd_b + i][kp2] = pk0;
            *(unsigned*)&sm.a.Vt[1][hd_b + i][kp2] = pk1;
        }
        if (p + 1 < npairs) {
            int nb0 = s_start + (p + 1) * 64;
            int nb1 = (nb0 + 32 > 2016) ? 2016 : (nb0 + 32);
            nb0 = (nb0 > 2016) ? 2016 : nb0;
            kr0 = *(const short8*)(kg + (size_t)(nb0 + key_a) * 4096 + hd_a);
            kr1 = *(const short8*)(kg + (size_t)(nb0 + key_a) * 4096 + hd_a + 8);
            vr0 = *(const short8*)(vg + (size_t)(nb0 + kp2) * 4096 + hd_b);
            vr1 = *(const short8*)(vg + (size_t)(nb0 + kp2 + 1) * 4096 + hd_b);
            kr2 = *(const short8*)(kg + (size_t)(nb1 + key_a) * 4096 + hd_a);
            kr3 = *(const short8*)(kg + (size_t)(nb1 + key_a) * 4096 + hd_a + 8);
            vr2 = *(const short8*)(vg + (size_t)(nb1 + kp2) * 4096 + hd_b);
            vr3 = *(const short8*)(vg + (size_t)(nb1 + kp2 + 1) * 4096 + hd_b);
        }
        __syncthreads();

        const int cidx  = 2 * p + par;
        const int base  = s_start + p * 64 + par * 32;
        const int dbase = trow0 - base;
        if (cidx < nch && dbase >= -15 && dbase <= 1054) {
            floatx4 S0 = (floatx4){0.f, 0.f, 0.f, 0.f};
            floatx4 S1 = (floatx4){0.f, 0.f, 0.f, 0.f};
#pragma unroll
            for (int kc = 0; kc < 4; ++kc) {
                short8 c0 = *(const short8*)&sm.a.Ks[par][lo][kc * 32 + quad * 8];
                short8 c1 = *(const short8*)&sm.a.Ks[par][16 + lo][kc * 32 + quad * 8];
                S0 = __builtin_amdgcn_mfma_f32_16x16x32_bf16(qf[kc], c0, S0, 0, 0, 0);
                S1 = __builtin_amdgcn_mfma_f32_16x16x32_bf16(qf[kc], c1, S1, 0, 0, 0);
            }
            short8 vfrag[8];
#pragma unroll
            for (int nt = 0; nt < 8; ++nt)
                vfrag[nt] = *(const short8*)&sm.a.Vt[par][nt * 16 + lo][quad * 8];

            const bool need_mask = !(dbase >= 31 && dbase <= 1008);
            const int dq = dbase + quad * 4 - lo;
            float lg[2][4];
#pragma unroll
            for (int tau = 0; tau < 2; ++tau) {
#pragma unroll
                for (int r = 0; r < 4; ++r) {
                    float sv = (tau == 0) ? S0[r] : S1[r];
                    float ax = fabsf(sv) * (2.0f / SOFT_CAP);
                    float e2 = __expf(-ax);
                    float th = (1.0f - e2) * __builtin_amdgcn_rcpf(1.0f + e2);
                    float l  = copysignf(SOFT_CAP * th, sv);
                    float p2 = __expf(l);
                    if (need_mask) {
                        int d = dq + r - tau * 16;
                        if ((unsigned)d > 1023u) p2 = 0.f;
                    }
                    lg[tau][r] = p2;
                }
            }
#pragma unroll
            for (int r = 0; r < 4; ++r) l_acc[r] += lg[0][r] + lg[1][r];

#pragma unroll
            for (int tau = 0; tau < 2; ++tau)
#pragma unroll
                for (int r = 0; r < 4; ++r)
                    sm.a.Ps[wave][quad * 4 + r][tau * 16 + lo] = f2b(lg[tau][r]);

            short8 pfrag = *(const short8*)&sm.a.Ps[wave][lo][quad * 8];
#pragma unroll
            for (int nt = 0; nt < 8; ++nt)
                O[nt] = __builtin_amdgcn_mfma_f32_16x16x32_bf16(pfrag, vfrag[nt], O[nt], 0, 0, 0);
        }
        __syncthreads();
    }

    // combine odd-parity partials into even-parity waves (linear: fixed-m)
    const int w2 = wave & 1;
    if (par == 1) {
#pragma unroll
        for (int r = 0; r < 4; ++r) sm.b.L[w2][r][lane] = l_acc[r];
#pragma unroll
        for (int nt = 0; nt < 8; ++nt)
#pragma unroll
            for (int r = 0; r < 4; ++r) sm.b.O[w2][nt][r][lane] = O[nt][r];
    }
    __syncthreads();
    if (par == 0) {
#pragma unroll
        for (int r = 0; r < 4; ++r) l_acc[r] += sm.b.L[w2][r][lane];
#pragma unroll
        for (int nt = 0; nt < 8; ++nt)
#pragma unroll
            for (int r = 0; r < 4; ++r) O[nt][r] += sm.b.O[w2][nt][r][lane];

#pragma unroll
        for (int xm = 1; xm < 16; xm <<= 1)
#pragma unroll
            for (int r = 0; r < 4; ++r) l_acc[r] += __shfl_xor(l_acc[r], xm, 64);
        float invl[4];
#pragma unroll
        for (int r = 0; r < 4; ++r) invl[r] = 1.0f / l_acc[r];

#pragma unroll
        for (int nt = 0; nt < 8; ++nt)
#pragma unroll
            for (int r = 0; r < 4; ++r) {
                int t = trow0 + quad * 4 + r;
                ebuf[(size_t)t * 2048 + n * 128 + nt * 16 + lo] = f2b(O[nt][r] * invl[r]);
            }
    }
}

// ---------------------------------------------------------------------------
extern "C" void kernel_launch(void* const* d_in, const int* in_sizes, int n_in,
                              void* d_out, int out_size, void* d_ws, size_t ws_size,
                              hipStream_t stream)
{
    const float* x   = (const float*)d_in[0];
    const int*  segp = (const int*)d_in[1];
    // d_in[2] = attn_mask (bool) -- redundant with causal+window predicate, ignored
    const float* qk  = (const float*)d_in[3];
    const float* kvk = (const float*)d_in[4];
    const float* ok  = (const float*)d_in[5];

    // Workspace (~50 MB): xb(0..8, aliased by ebuf) | WT_qkv(8..24.8) | WT_out(24.8..33.2) | qkvb(33.2..50)
    // QKV split-K partial P0 aliases d_out (16.8 MB, written last by add_out_k).
    // After attn_k: WT_qkv and qkvb are dead -> reused as fp32 split-K partials for out-proj.
    bf16* xb     = (bf16*)d_ws;
    bf16* ebuf   = xb;
    bf16* WT_qkv = xb + (size_t)4 * 1024 * 1024;
    bf16* WT_out = WT_qkv + (size_t)8 * 1024 * 1024;
    bf16* qkvb   = WT_out + (size_t)4 * 1024 * 1024;
    bf16* Q0     = (bf16*)d_out;           // qkv split-K partial (z=0)
    float* P0    = (float*)WT_qkv;
    float* P1    = (float*)qkvb;
    float* outp  = (float*)d_out;

    prep_k<<<dim3(14336), dim3(256), 0, stream>>>(x, qk, kvk, ok, xb, WT_qkv, WT_out);
    gemm_qkv_8ph_k<<<dim3(128, 2), dim3(512), 0, stream>>>(xb, WT_qkv, Q0, qkvb);
    qkv_add_k<<<dim3(4096), dim3(256), 0, stream>>>(Q0, qkvb);
    rope_kk<<<dim3(T_DIM), dim3(256), 0, stream>>>(qkvb, segp);
    attn_k<<<dim3(T_DIM / 32, N_HEADS), dim3(256), 0, stream>>>(qkvb, segp, ebuf);
    mfma_gemm_splitk_k<<<dim3(16, 16, 2), dim3(256), 0, stream>>>(
        ebuf, WT_out, P0, P1);
    add_out_k<<<dim3(4096), dim3(256), 0, stream>>>(P0, P1, outp);
}

// Round 5
// 254.069 us; speedup vs baseline: 1.0895x; 1.0895x over previous
//
#include <hip/hip_runtime.h>
#include <hip/hip_bf16.h>
#include <math.h>

// Problem constants (B=1)
#define T_DIM 2048
#define D_DIM 2048
#define N_HEADS 16
#define K_HEADS 8
#define H_DIM 128
#define WINDOW_SZ 1024
#define SOFT_CAP 50.0f
#define Q_SCALE 0.08838834764831845f   // 1/sqrt(128)
#define LN_BASE 9.210340371976184f     // ln(10000)

typedef __hip_bfloat16 bf16;
typedef __attribute__((ext_vector_type(8))) short short8;
typedef __attribute__((ext_vector_type(4))) float floatx4;

static __device__ __forceinline__ bf16 f2b(float v) { return __float2bfloat16(v); }
static __device__ __forceinline__ float b2f(bf16 v) { return __bfloat162float(v); }

// ---------------------------------------------------------------------------
// Fused prep: 1D grid.
//   [0, 8192)     : qkv weight transpose (32 matrices, 2048x128 -> rows z*128 of WT_qkv)
//   [8192, 12288) : out weight transpose (16 matrices, 128x2048 -> cols z*128 of WT_out)
//   [12288,14336) : x fp32 -> bf16 copy
// ---------------------------------------------------------------------------
__global__ __launch_bounds__(256) void prep_k(
    const float* __restrict__ x, const float* __restrict__ qk,
    const float* __restrict__ kvk, const float* __restrict__ ok,
    bf16* __restrict__ xb, bf16* __restrict__ WT_qkv, bf16* __restrict__ WT_out)
{
    __shared__ float tile[32][33];
    const int b = blockIdx.x;
    const int tid = threadIdx.x;
    const int tx = tid & 31, ty = tid >> 5;

    if (b < 8192) {
        const int z = b >> 8, rem = b & 255;
        const int c0 = (rem & 3) * 32;        // over H (128)
        const int r0 = (rem >> 2) * 32;       // over D (2048)
        const float* src = (z < 16) ? qk + (size_t)z * D_DIM * H_DIM
                                    : kvk + (size_t)(z - 16) * D_DIM * H_DIM;
        bf16* dst = WT_qkv + (size_t)z * 128 * 2048;
#pragma unroll
        for (int i = 0; i < 4; ++i)
            tile[ty + i * 8][tx] = src[(size_t)(r0 + ty + i * 8) * H_DIM + c0 + tx];
        __syncthreads();
#pragma unroll
        for (int i = 0; i < 4; ++i)
            dst[(size_t)(c0 + ty + i * 8) * 2048 + r0 + tx] = f2b(tile[tx][ty + i * 8]);
    } else if (b < 12288) {
        const int b2 = b - 8192;
        const int z = b2 >> 8, rem = b2 & 255;
        const int c0 = (rem & 63) * 32;       // over D (2048)
        const int r0 = (rem >> 6) * 32;       // over H (128)
        const float* src = ok + (size_t)z * H_DIM * D_DIM;
        bf16* dst = WT_out + (size_t)z * H_DIM;
#pragma unroll
        for (int i = 0; i < 4; ++i)
            tile[ty + i * 8][tx] = src[(size_t)(r0 + ty + i * 8) * D_DIM + c0 + tx];
        __syncthreads();
#pragma unroll
        for (int i = 0; i < 4; ++i)
            dst[(size_t)(c0 + ty + i * 8) * 2048 + r0 + tx] = f2b(tile[tx][ty + i * 8]);
    } else {
        const size_t i = ((size_t)(b - 12288) * 256 + tid) * 8;
        float4 a = *(const float4*)(x + i);
        float4 bb = *(const float4*)(x + i + 4);
        bf16 o[8] = {f2b(a.x), f2b(a.y), f2b(a.z), f2b(a.w),
                     f2b(bb.x), f2b(bb.y), f2b(bb.z), f2b(bb.w)};
        *(short8*)(xb + i) = *(const short8*)o;
    }
}

// ---------------------------------------------------------------------------
// 256x256 8-phase GEMM (T2+T3+T4+T5), QKV projection, SPLIT-K z=2 (verified r2).
// ---------------------------------------------------------------------------
static __device__ __forceinline__ void stageT(const bf16* __restrict__ gsrc,
                                              bf16* ldst, int h, int r, int kt)
{
    __builtin_amdgcn_global_load_lds(
        (const __attribute__((address_space(1))) void*)
            (gsrc + (size_t)((h * 128 + r * 64) * 2048 + kt * 64)),
        (__attribute__((address_space(3))) void*)(ldst + h * 8192 + r * 4096),
        16, 0, 0);
}

template <int MTB>
static __device__ __forceinline__ void readA4(short8 (&dst)[4][2], const bf16* base,
                                              int rlo, const int (&cs)[2])
{
#pragma unroll
    for (int mt = 0; mt < 4; ++mt)
#pragma unroll
        for (int ks = 0; ks < 2; ++ks)
            dst[mt][ks] = *(const short8*)&base[(rlo + (MTB + mt) * 16) * 64 + cs[ks]];
}

template <int NTB>
static __device__ __forceinline__ void readB2(short8 (&dst)[2][2], const bf16* base,
                                              int rlo, const int (&cs)[2])
{
#pragma unroll
    for (int n2 = 0; n2 < 2; ++n2)
#pragma unroll
        for (int ks = 0; ks < 2; ++ks)
            dst[n2][ks] = *(const short8*)&base[(rlo + (NTB + n2) * 16) * 64 + cs[ks]];
}

template <int MB, int NB>
static __device__ __forceinline__ void mfma16(floatx4 (&acc)[8][4],
                                              const short8 (&af)[4][2],
                                              const short8 (&bf)[2][2])
{
#pragma unroll
    for (int mt = 0; mt < 4; ++mt)
#pragma unroll
        for (int n2 = 0; n2 < 2; ++n2) {
            acc[MB + mt][NB + n2] = __builtin_amdgcn_mfma_f32_16x16x32_bf16(
                af[mt][0], bf[n2][0], acc[MB + mt][NB + n2], 0, 0, 0);
            acc[MB + mt][NB + n2] = __builtin_amdgcn_mfma_f32_16x16x32_bf16(
                af[mt][1], bf[n2][1], acc[MB + mt][NB + n2], 0, 0, 0);
        }
}

__global__ __launch_bounds__(512, 2) void gemm_qkv_8ph_k(
    const bf16* __restrict__ A, const bf16* __restrict__ BT,
    bf16* __restrict__ P0, bf16* __restrict__ P1)
{
    __shared__ alignas(16) bf16 lds[2][2][16384];   // [buf][A/B][256*64]

    const int tid  = threadIdx.x;
    const int lane = tid & 63;
    const int wave = tid >> 6;
    const int lo   = lane & 15;
    const int quad = lane >> 4;

    const int wg   = blockIdx.x;
    const int row0 = (wg & 7) * 256;
    const int col0 = (wg >> 3) * 256;
    const int kb   = blockIdx.y * 16;            // K-tile base (z * 1024 elems)
    bf16* __restrict__ Pd = blockIdx.y ? P1 : P0;

    const int wm   = (wave >> 2) * 128;   // WARPS_M = 2
    const int wn   = (wave & 3) * 64;     // WARPS_N = 4
    const int wmlo = wm + lo, wnlo = wn + lo;

    const int r_y   = wave * 8 + (lane >> 3);                   // 0..63
    const int c_src = ((lane & 7) ^ ((lane >> 3) & 7)) * 8;     // elements
    const bf16* pA = A  + (size_t)(row0 + r_y) * 2048 + c_src;
    const bf16* pB = BT + (size_t)(col0 + r_y) * 2048 + c_src;

    bf16* ldsA0 = &lds[0][0][0] + wave * 512;
    bf16* ldsB0 = &lds[0][1][0] + wave * 512;
    bf16* ldsA1 = &lds[1][0][0] + wave * 512;
    bf16* ldsB1 = &lds[1][1][0] + wave * 512;

    const int cs[2] = { (quad * 8) ^ ((lo & 7) << 3),
                        (32 + quad * 8) ^ ((lo & 7) << 3) };

    floatx4 acc[8][4];
#pragma unroll
    for (int i = 0; i < 8; ++i)
#pragma unroll
        for (int j = 0; j < 4; ++j) acc[i][j] = (floatx4){0.f, 0.f, 0.f, 0.f};

    stageT(pA, ldsA0, 0, 0, kb); stageT(pA, ldsA0, 0, 1, kb);
    stageT(pA, ldsA0, 1, 0, kb); stageT(pA, ldsA0, 1, 1, kb);
    stageT(pB, ldsB0, 0, 0, kb); stageT(pB, ldsB0, 0, 1, kb);
    stageT(pB, ldsB0, 1, 0, kb); stageT(pB, ldsB0, 1, 1, kb);
    stageT(pA, ldsA1, 0, 0, kb + 1); stageT(pA, ldsA1, 0, 1, kb + 1);
    stageT(pA, ldsA1, 1, 0, kb + 1); stageT(pA, ldsA1, 1, 1, kb + 1);
    stageT(pB, ldsB1, 0, 0, kb + 1); stageT(pB, ldsB1, 0, 1, kb + 1);
    asm volatile("s_waitcnt vmcnt(6)" ::: "memory");   // tile kb fully landed
    __builtin_amdgcn_s_barrier();

    short8 aF[4][2], a2F[4][2], bF[2][2], b2F[2][2];

#pragma unroll 1
    for (int i = 0; i < 8; ++i) {
        const int tb1  = kb + 2 * i + 1;
        const int lt0  = (2 * i + 2 < 16) ? 2 * i + 2 : 15;
        const int lt1  = (2 * i + 3 < 16) ? 2 * i + 3 : 15;
        const int tnx0 = kb + lt0;
        const int tnx1 = kb + lt1;

        // ======== group 0: compute K-tile kb+2i from buf0 ========
        readA4<0>(aF, &lds[0][0][0], wmlo, cs);
        readB2<0>(bF, &lds[0][1][0], wnlo, cs);
        stageT(pB, ldsB1, 1, 0, tb1); stageT(pB, ldsB1, 1, 1, tb1);
        __builtin_amdgcn_s_barrier();
        __builtin_amdgcn_s_setprio(1); mfma16<0, 0>(acc, aF, bF);   __builtin_amdgcn_s_setprio(0);
        __builtin_amdgcn_s_barrier();
        readA4<4>(a2F, &lds[0][0][0], wmlo, cs);
        readB2<2>(b2F, &lds[0][1][0], wnlo, cs);
        __builtin_amdgcn_s_barrier();
        __builtin_amdgcn_s_setprio(1); mfma16<4, 2>(acc, a2F, b2F); __builtin_amdgcn_s_setprio(0);
        __builtin_amdgcn_s_barrier();
        stageT(pA, ldsA0, 0, 0, tnx0); stageT(pA, ldsA0, 0, 1, tnx0);
        stageT(pA, ldsA0, 1, 0, tnx0); stageT(pA, ldsA0, 1, 1, tnx0);
        __builtin_amdgcn_s_barrier();
        __builtin_amdgcn_s_setprio(1); mfma16<0, 2>(acc, aF, b2F);  __builtin_amdgcn_s_setprio(0);
        __builtin_amdgcn_s_barrier();
        stageT(pB, ldsB0, 0, 0, tnx0); stageT(pB, ldsB0, 0, 1, tnx0);
        asm volatile("s_waitcnt vmcnt(6)" ::: "memory");
        __builtin_amdgcn_s_barrier();
        __builtin_amdgcn_s_setprio(1); mfma16<4, 0>(acc, a2F, bF);  __builtin_amdgcn_s_setprio(0);
        __builtin_amdgcn_s_barrier();

        // ======== group 1: compute K-tile kb+2i+1 from buf1 ========
        readA4<0>(aF, &lds[1][0][0], wmlo, cs);
        readB2<0>(bF, &lds[1][1][0], wnlo, cs);
        stageT(pB, ldsB0, 1, 0, tnx0); stageT(pB, ldsB0, 1, 1, tnx0);
        __builtin_amdgcn_s_barrier();
        __builtin_amdgcn_s_setprio(1); mfma16<0, 0>(acc, aF, bF);   __builtin_amdgcn_s_setprio(0);
        __builtin_amdgcn_s_barrier();
        readA4<4>(a2F, &lds[1][0][0], wmlo, cs);
        readB2<2>(b2F, &lds[1][1][0], wnlo, cs);
        __builtin_amdgcn_s_barrier();
        __builtin_amdgcn_s_setprio(1); mfma16<4, 2>(acc, a2F, b2F); __builtin_amdgcn_s_setprio(0);
        __builtin_amdgcn_s_barrier();
        stageT(pA, ldsA1, 0, 0, tnx1); stageT(pA, ldsA1, 0, 1, tnx1);
        stageT(pA, ldsA1, 1, 0, tnx1); stageT(pA, ldsA1, 1, 1, tnx1);
        __builtin_amdgcn_s_barrier();
        __builtin_amdgcn_s_setprio(1); mfma16<0, 2>(acc, aF, b2F);  __builtin_amdgcn_s_setprio(0);
        __builtin_amdgcn_s_barrier();
        stageT(pB, ldsB1, 0, 0, tnx1); stageT(pB, ldsB1, 0, 1, tnx1);
        asm volatile("s_waitcnt vmcnt(6)" ::: "memory");
        __builtin_amdgcn_s_barrier();
        __builtin_amdgcn_s_setprio(1); mfma16<4, 0>(acc, a2F, bF);  __builtin_amdgcn_s_setprio(0);
        __builtin_amdgcn_s_barrier();
    }

#pragma unroll
    for (int mt = 0; mt < 8; ++mt)
#pragma unroll
        for (int nt = 0; nt < 4; ++nt)
#pragma unroll
            for (int r = 0; r < 4; ++r) {
                int rr = row0 + wm + mt * 16 + quad * 4 + r;
                int cc = col0 + wn + nt * 16 + lo;
                Pd[(size_t)rr * 4096 + cc] = f2b(acc[mt][nt][r]);
            }
}

// ---------------------------------------------------------------------------
// Fused: qkvb = Q0 + qkvb, then RoPE on the K region (round-4 fusion of
// qkv_add_k + rope_kk). One block per t-row; threads 0-127 add Q,
// 128-191 add+rope K (both halves), 192-255 add V.
// ---------------------------------------------------------------------------
__global__ __launch_bounds__(256) void qkv_addrope_k(
    const bf16* __restrict__ Q0, bf16* __restrict__ qkvb,
    const int* __restrict__ segpos)
{
    const int t = blockIdx.x;
    const int tid = threadIdx.x;
    const size_t row = (size_t)t * 4096;

    if (tid < 128 || tid >= 192) {
        // Q region (threads 0..127 -> 2048 elems) / V region (192..255 -> 1024)
        const size_t i = (tid < 128) ? row + (size_t)tid * 16
                                     : row + 3072 + (size_t)(tid - 192) * 16;
#pragma unroll
        for (int h = 0; h < 2; ++h) {
            short8 a = *(const short8*)(Q0 + i + h * 8);
            short8 b = *(const short8*)(qkvb + i + h * 8);
            const bf16* ap = (const bf16*)&a;
            const bf16* bp = (const bf16*)&b;
            bf16 o[8];
#pragma unroll
            for (int j = 0; j < 8; ++j) o[j] = f2b(b2f(ap[j]) + b2f(bp[j]));
            *(short8*)(qkvb + i + h * 8) = *(const short8*)o;
        }
    } else {
        // K region: 64 threads, each owns 8 first-half + 8 second-half elems
        const int k = tid - 128;
        const float pos = (float)segpos[t];
        const size_t base = row + 2048 + (size_t)(k >> 3) * 128 + (k & 7) * 8;
        short8 aF = *(const short8*)(Q0 + base);
        short8 bF = *(const short8*)(qkvb + base);
        short8 aS = *(const short8*)(Q0 + base + 64);
        short8 bS = *(const short8*)(qkvb + base + 64);
        const bf16* afp = (const bf16*)&aF;
        const bf16* bfp = (const bf16*)&bF;
        const bf16* asp = (const bf16*)&aS;
        const bf16* bsp = (const bf16*)&bS;
        bf16 oF[8], oS[8];
#pragma unroll
        for (int j = 0; j < 8; ++j) {
            const int hp = (k & 7) * 8 + j;
            float first  = b2f(afp[j]) + b2f(bfp[j]);
            float second = b2f(asp[j]) + b2f(bsp[j]);
            float ang = pos * __expf(-(float)hp * (1.0f / 64.0f) * LN_BASE);
            float sv, cv; __sincosf(ang, &sv, &cv);
            oF[j] = f2b(first * cv - second * sv);
            oS[j] = f2b(second * cv + first * sv);
        }
        *(short8*)(qkvb + base)      = *(const short8*)oF;
        *(short8*)(qkvb + base + 64) = *(const short8*)oS;
    }
}

// ---------------------------------------------------------------------------
// Split-K MFMA GEMM: grid.z selects K-half; writes fp32 partials.
// 128x128 tile (m97 structure); Ndim=2048, K-half = 1024.
// ---------------------------------------------------------------------------
__global__ __launch_bounds__(256) void mfma_gemm_splitk_k(
    const bf16* __restrict__ A, const bf16* __restrict__ BT,
    float* __restrict__ P0, float* __restrict__ P1)
{
    __shared__ alignas(16) bf16 As[128 * 32];
    __shared__ alignas(16) bf16 Bs[128 * 32];

    const int tid  = threadIdx.x;
    const int lane = tid & 63;
    const int wave = tid >> 6;
    const int lo   = lane & 15;
    const int quad = lane >> 4;
    const int row0 = blockIdx.x * 128;
    const int col0 = blockIdx.y * 128;
    const int kbeg = blockIdx.z * 1024;
    float* __restrict__ P = blockIdx.z ? P1 : P0;
    const int wm = (wave >> 1) * 64;
    const int wn = (wave & 1) * 64;

    const int lrow = lane >> 2;
    const int lcol = ((lane & 3) ^ ((lane >> 3) & 3)) * 8;
    const int swk  = (quad ^ ((lo >> 1) & 3)) * 8;

    floatx4 acc[4][4];
#pragma unroll
    for (int i = 0; i < 4; ++i)
#pragma unroll
        for (int j = 0; j < 4; ++j) acc[i][j] = (floatx4){0.f, 0.f, 0.f, 0.f};

    for (int k0 = kbeg; k0 < kbeg + 1024; k0 += 32) {
        __syncthreads();
#pragma unroll
        for (int i = 0; i < 2; ++i) {
            const int trow = wave * 32 + i * 16 + lrow;
            const bf16* ga = A  + (size_t)(row0 + trow) * 2048 + k0 + lcol;
            const bf16* gb = BT + (size_t)(col0 + trow) * 2048 + k0 + lcol;
            __builtin_amdgcn_global_load_lds(
                (const __attribute__((address_space(1))) void*)ga,
                (__attribute__((address_space(3))) void*)(As + (wave * 2 + i) * 512),
                16, 0, 0);
            __builtin_amdgcn_global_load_lds(
                (const __attribute__((address_space(1))) void*)gb,
                (__attribute__((address_space(3))) void*)(Bs + (wave * 2 + i) * 512),
                16, 0, 0);
        }
        __syncthreads();

        short8 af[4], bfr[4];
#pragma unroll
        for (int mt = 0; mt < 4; ++mt)
            af[mt] = *(const short8*)&As[(wm + mt * 16 + lo) * 32 + swk];
#pragma unroll
        for (int nt = 0; nt < 4; ++nt)
            bfr[nt] = *(const short8*)&Bs[(wn + nt * 16 + lo) * 32 + swk];
#pragma unroll
        for (int mt = 0; mt < 4; ++mt)
#pragma unroll
            for (int nt = 0; nt < 4; ++nt)
                acc[mt][nt] = __builtin_amdgcn_mfma_f32_16x16x32_bf16(
                    af[mt], bfr[nt], acc[mt][nt], 0, 0, 0);
    }

#pragma unroll
    for (int mt = 0; mt < 4; ++mt)
#pragma unroll
        for (int nt = 0; nt < 4; ++nt)
#pragma unroll
            for (int r = 0; r < 4; ++r) {
                int rr = row0 + wm + mt * 16 + quad * 4 + r;
                int cc = col0 + wn + nt * 16 + lo;
                P[(size_t)rr * 2048 + cc] = acc[mt][nt][r];
            }
}

// ---------------------------------------------------------------------------
// out = P0 + P1 (float4, 4 elems/thread)
// ---------------------------------------------------------------------------
__global__ __launch_bounds__(256) void add_out_k(
    const float* __restrict__ P0, const float* __restrict__ P1,
    float* __restrict__ out)
{
    const size_t i = ((size_t)blockIdx.x * 256 + threadIdx.x) * 4;
    float4 a = *(const float4*)(P0 + i);
    float4 b = *(const float4*)(P1 + i);
    float4 o = {a.x + b.x, a.y + b.y, a.z + b.z, a.w + b.w};
    *(float4*)(out + i) = o;
}

// ---------------------------------------------------------------------------
// Flash MFMA attention, fixed-m softmax (softcap bounds logits to ±50).
// Body = round-1 verified (54.6 us). Round-4 change: 1D grid with heavy/light
// remap — ids [0,256) are heavy blocks (bx>=16, 34 chunks), ids [256,512)
// light (bx<16, 2bx+2 chunks). Round-robin dispatch pairs one heavy + one
// light per CU (2 blocks/CU) -> per-CU load ~51 units instead of worst 68.
// ---------------------------------------------------------------------------
__global__ __launch_bounds__(256) void attn_k(
    const bf16* __restrict__ qkvb, const int* __restrict__ segpos,
    bf16* __restrict__ ebuf)
{
    __shared__ alignas(16) bf16 Ks[2][32][136];
    __shared__ alignas(16) bf16 Vt[2][128][40];
    __shared__ alignas(16) bf16 Ps[4][16][40];

    const int id = blockIdx.x;
    int bxi, n;
    if (id < 256) { bxi = 16 + (id & 15); n = id >> 4; }     // heavy
    else          { int j = id - 256; bxi = j & 15; n = j >> 4; }  // light
    const int t0 = bxi * 64;
    const int kh = n >> 1;
    const int tid  = threadIdx.x;
    const int lane = tid & 63;
    const int wave = tid >> 6;
    const int lo   = lane & 15;
    const int quad = lane >> 4;
    const int twlo = t0 + wave * 16;

    short8 qf[4];
    {
        const int tq = twlo + lo;
        const float pos = (float)segpos[tq];
        const bf16* qp = qkvb + (size_t)tq * 4096 + n * 128;
        float qv[4][8];
#pragma unroll
        for (int kc = 0; kc < 4; ++kc) {
            short8 raw = *(const short8*)(qp + kc * 32 + quad * 8);
            const bf16* rb = (const bf16*)&raw;
#pragma unroll
            for (int j = 0; j < 8; ++j) qv[kc][j] = b2f(rb[j]);
        }
#pragma unroll
        for (int kc = 0; kc < 2; ++kc)
#pragma unroll
            for (int j = 0; j < 8; ++j) {
                int hp = kc * 32 + quad * 8 + j;
                float ang = pos * __expf(-(float)hp * (1.0f / 64.0f) * LN_BASE);
                float sv, cv; __sincosf(ang, &sv, &cv);
                float first = qv[kc][j], second = qv[kc + 2][j];
                qv[kc][j]     = (first * cv - second * sv) * Q_SCALE;
                qv[kc + 2][j] = (second * cv + first * sv) * Q_SCALE;
            }
#pragma unroll
        for (int kc = 0; kc < 4; ++kc) {
            bf16 o[8];
#pragma unroll
            for (int j = 0; j < 8; ++j) o[j] = f2b(qv[kc][j]);
            qf[kc] = *(const short8*)o;
        }
    }

    floatx4 O[8];
#pragma unroll
    for (int i = 0; i < 8; ++i) O[i] = (floatx4){0.f, 0.f, 0.f, 0.f};
    float l_acc[4] = {0.f, 0.f, 0.f, 0.f};

    const int key_a = tid >> 3,      hd_a = (tid & 7) * 16;
    const int kp2   = (tid & 15) * 2, hd_b = (tid >> 4) * 8;

    const int s_start = (t0 > 1023) ? (t0 - 1024) : 0;
    const int nch = (t0 + 63 - s_start) / 32 + 1;

    const bf16* kg = qkvb + 2048 + kh * 128;
    const bf16* vg = qkvb + 3072 + kh * 128;

    short8 kr0 = *(const short8*)(kg + (size_t)(s_start + key_a) * 4096 + hd_a);
    short8 kr1 = *(const short8*)(kg + (size_t)(s_start + key_a) * 4096 + hd_a + 8);
    short8 vr0 = *(const short8*)(vg + (size_t)(s_start + kp2) * 4096 + hd_b);
    short8 vr1 = *(const short8*)(vg + (size_t)(s_start + kp2 + 1) * 4096 + hd_b);

    for (int c = 0; c < nch; ++c) {
        const int base = s_start + c * 32;
        const int buf = c & 1;

        *(short8*)&Ks[buf][key_a][hd_a]     = kr0;
        *(short8*)&Ks[buf][key_a][hd_a + 8] = kr1;
#pragma unroll
        for (int i = 0; i < 8; ++i) {
            unsigned pk = (unsigned)(unsigned short)vr0[i] |
                          ((unsigned)(unsigned short)vr1[i] << 16);
            *(unsigned*)&Vt[buf][hd_b + i][kp2] = pk;
        }
        if (c + 1 < nch) {
            const int nb = base + 32;
            kr0 = *(const short8*)(kg + (size_t)(nb + key_a) * 4096 + hd_a);
            kr1 = *(const short8*)(kg + (size_t)(nb + key_a) * 4096 + hd_a + 8);
            vr0 = *(const short8*)(vg + (size_t)(nb + kp2) * 4096 + hd_b);
            vr1 = *(const short8*)(vg + (size_t)(nb + kp2 + 1) * 4096 + hd_b);
        }
        __syncthreads();

        const int dbase = twlo - base;
        if (dbase >= -15 && dbase <= 1054) {
            floatx4 S0 = (floatx4){0.f, 0.f, 0.f, 0.f};
            floatx4 S1 = (floatx4){0.f, 0.f, 0.f, 0.f};
#pragma unroll
            for (int kc = 0; kc < 4; ++kc) {
                short8 b0 = *(const short8*)&Ks[buf][lo][kc * 32 + quad * 8];
                short8 b1 = *(const short8*)&Ks[buf][16 + lo][kc * 32 + quad * 8];
                S0 = __builtin_amdgcn_mfma_f32_16x16x32_bf16(qf[kc], b0, S0, 0, 0, 0);
                S1 = __builtin_amdgcn_mfma_f32_16x16x32_bf16(qf[kc], b1, S1, 0, 0, 0);
            }
            short8 vfrag[8];
#pragma unroll
            for (int nt = 0; nt < 8; ++nt)
                vfrag[nt] = *(const short8*)&Vt[buf][nt * 16 + lo][quad * 8];

            const bool need_mask = !(dbase >= 31 && dbase <= 1008);
            const int dq = dbase + quad * 4 - lo;
            float lg[2][4];
#pragma unroll
            for (int tau = 0; tau < 2; ++tau) {
#pragma unroll
                for (int r = 0; r < 4; ++r) {
                    float sv = (tau == 0) ? S0[r] : S1[r];
                    float ax = fabsf(sv) * (2.0f / SOFT_CAP);
                    float e2 = __expf(-ax);
                    float th = (1.0f - e2) * __builtin_amdgcn_rcpf(1.0f + e2);
                    float l  = copysignf(SOFT_CAP * th, sv);
                    float p  = __expf(l);
                    if (need_mask) {
                        int d = dq + r - tau * 16;
                        if ((unsigned)d > 1023u) p = 0.f;
                    }
                    lg[tau][r] = p;
                }
            }
#pragma unroll
            for (int r = 0; r < 4; ++r) l_acc[r] += lg[0][r] + lg[1][r];

#pragma unroll
            for (int tau = 0; tau < 2; ++tau)
#pragma unroll
                for (int r = 0; r < 4; ++r)
                    Ps[wave][quad * 4 + r][tau * 16 + lo] = f2b(lg[tau][r]);

            short8 pfrag = *(const short8*)&Ps[wave][lo][quad * 8];
#pragma unroll
            for (int nt = 0; nt < 8; ++nt)
                O[nt] = __builtin_amdgcn_mfma_f32_16x16x32_bf16(pfrag, vfrag[nt], O[nt], 0, 0, 0);
        }
    }

#pragma unroll
    for (int xm = 1; xm < 16; xm <<= 1)
#pragma unroll
        for (int r = 0; r < 4; ++r) l_acc[r] += __shfl_xor(l_acc[r], xm, 64);
    float invl[4];
#pragma unroll
    for (int r = 0; r < 4; ++r) invl[r] = 1.0f / l_acc[r];

#pragma unroll
    for (int nt = 0; nt < 8; ++nt)
#pragma unroll
        for (int r = 0; r < 4; ++r) {
            int t = twlo + quad * 4 + r;
            ebuf[(size_t)t * 2048 + n * 128 + nt * 16 + lo] = f2b(O[nt][r] * invl[r]);
        }
}

// ---------------------------------------------------------------------------
extern "C" void kernel_launch(void* const* d_in, const int* in_sizes, int n_in,
                              void* d_out, int out_size, void* d_ws, size_t ws_size,
                              hipStream_t stream)
{
    const float* x   = (const float*)d_in[0];
    const int*  segp = (const int*)d_in[1];
    // d_in[2] = attn_mask (bool) -- redundant with causal+window predicate, ignored
    const float* qk  = (const float*)d_in[3];
    const float* kvk = (const float*)d_in[4];
    const float* ok  = (const float*)d_in[5];

    // Workspace (~50 MB): xb(0..8, aliased by ebuf) | WT_qkv(8..24.8) | WT_out(24.8..33.2) | qkvb(33.2..50)
    // QKV split-K partial Q0 aliases d_out (16.8 MB, written last by add_out_k).
    // After attn_k: WT_qkv and qkvb are dead -> reused as fp32 split-K partials for out-proj.
    bf16* xb     = (bf16*)d_ws;
    bf16* ebuf   = xb;
    bf16* WT_qkv = xb + (size_t)4 * 1024 * 1024;
    bf16* WT_out = WT_qkv + (size_t)8 * 1024 * 1024;
    bf16* qkvb   = WT_out + (size_t)4 * 1024 * 1024;
    bf16* Q0     = (bf16*)d_out;           // qkv split-K partial (z=0)
    float* P0    = (float*)WT_qkv;
    float* P1    = (float*)qkvb;
    float* outp  = (float*)d_out;

    prep_k<<<dim3(14336), dim3(256), 0, stream>>>(x, qk, kvk, ok, xb, WT_qkv, WT_out);
    gemm_qkv_8ph_k<<<dim3(128, 2), dim3(512), 0, stream>>>(xb, WT_qkv, Q0, qkvb);
    qkv_addrope_k<<<dim3(T_DIM), dim3(256), 0, stream>>>(Q0, qkvb, segp);
    attn_k<<<dim3(512), dim3(256), 0, stream>>>(qkvb, segp, ebuf);
    mfma_gemm_splitk_k<<<dim3(16, 16, 2), dim3(256), 0, stream>>>(
        ebuf, WT_out, P0, P1);
    add_out_k<<<dim3(4096), dim3(256), 0, stream>>>(P0, P1, outp);
}

// Round 6
// 251.543 us; speedup vs baseline: 1.1004x; 1.0100x over previous
//
#include <hip/hip_runtime.h>
#include <hip/hip_bf16.h>
#include <math.h>

// Problem constants (B=1)
#define T_DIM 2048
#define D_DIM 2048
#define N_HEADS 16
#define K_HEADS 8
#define H_DIM 128
#define WINDOW_SZ 1024
#define SOFT_CAP 50.0f
#define Q_SCALE 0.08838834764831845f   // 1/sqrt(128)
#define LN_BASE 9.210340371976184f     // ln(10000)

typedef __hip_bfloat16 bf16;
typedef __attribute__((ext_vector_type(8))) short short8;
typedef __attribute__((ext_vector_type(4))) float floatx4;

static __device__ __forceinline__ bf16 f2b(float v) { return __float2bfloat16(v); }
static __device__ __forceinline__ float b2f(bf16 v) { return __bfloat162float(v); }

// ---------------------------------------------------------------------------
// Fused prep: 1D grid.
//   [0, 8192)     : qkv weight transpose (32 matrices, 2048x128 -> rows z*128 of WT_qkv)
//   [8192, 12288) : out weight transpose (16 matrices, 128x2048 -> cols z*128 of WT_out)
//   [12288,14336) : x fp32 -> bf16 copy
// ---------------------------------------------------------------------------
__global__ __launch_bounds__(256) void prep_k(
    const float* __restrict__ x, const float* __restrict__ qk,
    const float* __restrict__ kvk, const float* __restrict__ ok,
    bf16* __restrict__ xb, bf16* __restrict__ WT_qkv, bf16* __restrict__ WT_out)
{
    __shared__ float tile[32][33];
    const int b = blockIdx.x;
    const int tid = threadIdx.x;
    const int tx = tid & 31, ty = tid >> 5;

    if (b < 8192) {
        const int z = b >> 8, rem = b & 255;
        const int c0 = (rem & 3) * 32;        // over H (128)
        const int r0 = (rem >> 2) * 32;       // over D (2048)
        const float* src = (z < 16) ? qk + (size_t)z * D_DIM * H_DIM
                                    : kvk + (size_t)(z - 16) * D_DIM * H_DIM;
        bf16* dst = WT_qkv + (size_t)z * 128 * 2048;
#pragma unroll
        for (int i = 0; i < 4; ++i)
            tile[ty + i * 8][tx] = src[(size_t)(r0 + ty + i * 8) * H_DIM + c0 + tx];
        __syncthreads();
#pragma unroll
        for (int i = 0; i < 4; ++i)
            dst[(size_t)(c0 + ty + i * 8) * 2048 + r0 + tx] = f2b(tile[tx][ty + i * 8]);
    } else if (b < 12288) {
        const int b2 = b - 8192;
        const int z = b2 >> 8, rem = b2 & 255;
        const int c0 = (rem & 63) * 32;       // over D (2048)
        const int r0 = (rem >> 6) * 32;       // over H (128)
        const float* src = ok + (size_t)z * H_DIM * D_DIM;
        bf16* dst = WT_out + (size_t)z * H_DIM;
#pragma unroll
        for (int i = 0; i < 4; ++i)
            tile[ty + i * 8][tx] = src[(size_t)(r0 + ty + i * 8) * D_DIM + c0 + tx];
        __syncthreads();
#pragma unroll
        for (int i = 0; i < 4; ++i)
            dst[(size_t)(c0 + ty + i * 8) * 2048 + r0 + tx] = f2b(tile[tx][ty + i * 8]);
    } else {
        const size_t i = ((size_t)(b - 12288) * 256 + tid) * 8;
        float4 a = *(const float4*)(x + i);
        float4 bb = *(const float4*)(x + i + 4);
        bf16 o[8] = {f2b(a.x), f2b(a.y), f2b(a.z), f2b(a.w),
                     f2b(bb.x), f2b(bb.y), f2b(bb.z), f2b(bb.w)};
        *(short8*)(xb + i) = *(const short8*)o;
    }
}

// ---------------------------------------------------------------------------
// 256x256 8-phase GEMM (T2+T3+T4+T5), QKV projection, SPLIT-K z=2 (verified r2).
// ---------------------------------------------------------------------------
static __device__ __forceinline__ void stageT(const bf16* __restrict__ gsrc,
                                              bf16* ldst, int h, int r, int kt)
{
    __builtin_amdgcn_global_load_lds(
        (const __attribute__((address_space(1))) void*)
            (gsrc + (size_t)((h * 128 + r * 64) * 2048 + kt * 64)),
        (__attribute__((address_space(3))) void*)(ldst + h * 8192 + r * 4096),
        16, 0, 0);
}

template <int MTB>
static __device__ __forceinline__ void readA4(short8 (&dst)[4][2], const bf16* base,
                                              int rlo, const int (&cs)[2])
{
#pragma unroll
    for (int mt = 0; mt < 4; ++mt)
#pragma unroll
        for (int ks = 0; ks < 2; ++ks)
            dst[mt][ks] = *(const short8*)&base[(rlo + (MTB + mt) * 16) * 64 + cs[ks]];
}

template <int NTB>
static __device__ __forceinline__ void readB2(short8 (&dst)[2][2], const bf16* base,
                                              int rlo, const int (&cs)[2])
{
#pragma unroll
    for (int n2 = 0; n2 < 2; ++n2)
#pragma unroll
        for (int ks = 0; ks < 2; ++ks)
            dst[n2][ks] = *(const short8*)&base[(rlo + (NTB + n2) * 16) * 64 + cs[ks]];
}

template <int MB, int NB>
static __device__ __forceinline__ void mfma16(floatx4 (&acc)[8][4],
                                              const short8 (&af)[4][2],
                                              const short8 (&bf)[2][2])
{
#pragma unroll
    for (int mt = 0; mt < 4; ++mt)
#pragma unroll
        for (int n2 = 0; n2 < 2; ++n2) {
            acc[MB + mt][NB + n2] = __builtin_amdgcn_mfma_f32_16x16x32_bf16(
                af[mt][0], bf[n2][0], acc[MB + mt][NB + n2], 0, 0, 0);
            acc[MB + mt][NB + n2] = __builtin_amdgcn_mfma_f32_16x16x32_bf16(
                af[mt][1], bf[n2][1], acc[MB + mt][NB + n2], 0, 0, 0);
        }
}

__global__ __launch_bounds__(512, 2) void gemm_qkv_8ph_k(
    const bf16* __restrict__ A, const bf16* __restrict__ BT,
    bf16* __restrict__ P0, bf16* __restrict__ P1)
{
    __shared__ alignas(16) bf16 lds[2][2][16384];   // [buf][A/B][256*64]

    const int tid  = threadIdx.x;
    const int lane = tid & 63;
    const int wave = tid >> 6;
    const int lo   = lane & 15;
    const int quad = lane >> 4;

    const int wg   = blockIdx.x;
    const int row0 = (wg & 7) * 256;
    const int col0 = (wg >> 3) * 256;
    const int kb   = blockIdx.y * 16;            // K-tile base (z * 1024 elems)
    bf16* __restrict__ Pd = blockIdx.y ? P1 : P0;

    const int wm   = (wave >> 2) * 128;   // WARPS_M = 2
    const int wn   = (wave & 3) * 64;     // WARPS_N = 4
    const int wmlo = wm + lo, wnlo = wn + lo;

    const int r_y   = wave * 8 + (lane >> 3);                   // 0..63
    const int c_src = ((lane & 7) ^ ((lane >> 3) & 7)) * 8;     // elements
    const bf16* pA = A  + (size_t)(row0 + r_y) * 2048 + c_src;
    const bf16* pB = BT + (size_t)(col0 + r_y) * 2048 + c_src;

    bf16* ldsA0 = &lds[0][0][0] + wave * 512;
    bf16* ldsB0 = &lds[0][1][0] + wave * 512;
    bf16* ldsA1 = &lds[1][0][0] + wave * 512;
    bf16* ldsB1 = &lds[1][1][0] + wave * 512;

    const int cs[2] = { (quad * 8) ^ ((lo & 7) << 3),
                        (32 + quad * 8) ^ ((lo & 7) << 3) };

    floatx4 acc[8][4];
#pragma unroll
    for (int i = 0; i < 8; ++i)
#pragma unroll
        for (int j = 0; j < 4; ++j) acc[i][j] = (floatx4){0.f, 0.f, 0.f, 0.f};

    stageT(pA, ldsA0, 0, 0, kb); stageT(pA, ldsA0, 0, 1, kb);
    stageT(pA, ldsA0, 1, 0, kb); stageT(pA, ldsA0, 1, 1, kb);
    stageT(pB, ldsB0, 0, 0, kb); stageT(pB, ldsB0, 0, 1, kb);
    stageT(pB, ldsB0, 1, 0, kb); stageT(pB, ldsB0, 1, 1, kb);
    stageT(pA, ldsA1, 0, 0, kb + 1); stageT(pA, ldsA1, 0, 1, kb + 1);
    stageT(pA, ldsA1, 1, 0, kb + 1); stageT(pA, ldsA1, 1, 1, kb + 1);
    stageT(pB, ldsB1, 0, 0, kb + 1); stageT(pB, ldsB1, 0, 1, kb + 1);
    asm volatile("s_waitcnt vmcnt(6)" ::: "memory");   // tile kb fully landed
    __builtin_amdgcn_s_barrier();

    short8 aF[4][2], a2F[4][2], bF[2][2], b2F[2][2];

#pragma unroll 1
    for (int i = 0; i < 8; ++i) {
        const int tb1  = kb + 2 * i + 1;
        const int lt0  = (2 * i + 2 < 16) ? 2 * i + 2 : 15;
        const int lt1  = (2 * i + 3 < 16) ? 2 * i + 3 : 15;
        const int tnx0 = kb + lt0;
        const int tnx1 = kb + lt1;

        // ======== group 0: compute K-tile kb+2i from buf0 ========
        readA4<0>(aF, &lds[0][0][0], wmlo, cs);
        readB2<0>(bF, &lds[0][1][0], wnlo, cs);
        stageT(pB, ldsB1, 1, 0, tb1); stageT(pB, ldsB1, 1, 1, tb1);
        __builtin_amdgcn_s_barrier();
        __builtin_amdgcn_s_setprio(1); mfma16<0, 0>(acc, aF, bF);   __builtin_amdgcn_s_setprio(0);
        __builtin_amdgcn_s_barrier();
        readA4<4>(a2F, &lds[0][0][0], wmlo, cs);
        readB2<2>(b2F, &lds[0][1][0], wnlo, cs);
        __builtin_amdgcn_s_barrier();
        __builtin_amdgcn_s_setprio(1); mfma16<4, 2>(acc, a2F, b2F); __builtin_amdgcn_s_setprio(0);
        __builtin_amdgcn_s_barrier();
        stageT(pA, ldsA0, 0, 0, tnx0); stageT(pA, ldsA0, 0, 1, tnx0);
        stageT(pA, ldsA0, 1, 0, tnx0); stageT(pA, ldsA0, 1, 1, tnx0);
        __builtin_amdgcn_s_barrier();
        __builtin_amdgcn_s_setprio(1); mfma16<0, 2>(acc, aF, b2F);  __builtin_amdgcn_s_setprio(0);
        __builtin_amdgcn_s_barrier();
        stageT(pB, ldsB0, 0, 0, tnx0); stageT(pB, ldsB0, 0, 1, tnx0);
        asm volatile("s_waitcnt vmcnt(6)" ::: "memory");
        __builtin_amdgcn_s_barrier();
        __builtin_amdgcn_s_setprio(1); mfma16<4, 0>(acc, a2F, bF);  __builtin_amdgcn_s_setprio(0);
        __builtin_amdgcn_s_barrier();

        // ======== group 1: compute K-tile kb+2i+1 from buf1 ========
        readA4<0>(aF, &lds[1][0][0], wmlo, cs);
        readB2<0>(bF, &lds[1][1][0], wnlo, cs);
        stageT(pB, ldsB0, 1, 0, tnx0); stageT(pB, ldsB0, 1, 1, tnx0);
        __builtin_amdgcn_s_barrier();
        __builtin_amdgcn_s_setprio(1); mfma16<0, 0>(acc, aF, bF);   __builtin_amdgcn_s_setprio(0);
        __builtin_amdgcn_s_barrier();
        readA4<4>(a2F, &lds[1][0][0], wmlo, cs);
        readB2<2>(b2F, &lds[1][1][0], wnlo, cs);
        __builtin_amdgcn_s_barrier();
        __builtin_amdgcn_s_setprio(1); mfma16<4, 2>(acc, a2F, b2F); __builtin_amdgcn_s_setprio(0);
        __builtin_amdgcn_s_barrier();
        stageT(pA, ldsA1, 0, 0, tnx1); stageT(pA, ldsA1, 0, 1, tnx1);
        stageT(pA, ldsA1, 1, 0, tnx1); stageT(pA, ldsA1, 1, 1, tnx1);
        __builtin_amdgcn_s_barrier();
        __builtin_amdgcn_s_setprio(1); mfma16<0, 2>(acc, aF, b2F);  __builtin_amdgcn_s_setprio(0);
        __builtin_amdgcn_s_barrier();
        stageT(pB, ldsB1, 0, 0, tnx1); stageT(pB, ldsB1, 0, 1, tnx1);
        asm volatile("s_waitcnt vmcnt(6)" ::: "memory");
        __builtin_amdgcn_s_barrier();
        __builtin_amdgcn_s_setprio(1); mfma16<4, 0>(acc, a2F, bF);  __builtin_amdgcn_s_setprio(0);
        __builtin_amdgcn_s_barrier();
    }

#pragma unroll
    for (int mt = 0; mt < 8; ++mt)
#pragma unroll
        for (int nt = 0; nt < 4; ++nt)
#pragma unroll
            for (int r = 0; r < 4; ++r) {
                int rr = row0 + wm + mt * 16 + quad * 4 + r;
                int cc = col0 + wn + nt * 16 + lo;
                Pd[(size_t)rr * 4096 + cc] = f2b(acc[mt][nt][r]);
            }
}

// ---------------------------------------------------------------------------
// Fused: qkvb = Q0 + qkvb, then RoPE on the K region (verified r5).
// ---------------------------------------------------------------------------
__global__ __launch_bounds__(256) void qkv_addrope_k(
    const bf16* __restrict__ Q0, bf16* __restrict__ qkvb,
    const int* __restrict__ segpos)
{
    const int t = blockIdx.x;
    const int tid = threadIdx.x;
    const size_t row = (size_t)t * 4096;

    if (tid < 128 || tid >= 192) {
        // Q region (threads 0..127 -> 2048 elems) / V region (192..255 -> 1024)
        const size_t i = (tid < 128) ? row + (size_t)tid * 16
                                     : row + 3072 + (size_t)(tid - 192) * 16;
#pragma unroll
        for (int h = 0; h < 2; ++h) {
            short8 a = *(const short8*)(Q0 + i + h * 8);
            short8 b = *(const short8*)(qkvb + i + h * 8);
            const bf16* ap = (const bf16*)&a;
            const bf16* bp = (const bf16*)&b;
            bf16 o[8];
#pragma unroll
            for (int j = 0; j < 8; ++j) o[j] = f2b(b2f(ap[j]) + b2f(bp[j]));
            *(short8*)(qkvb + i + h * 8) = *(const short8*)o;
        }
    } else {
        // K region: 64 threads, each owns 8 first-half + 8 second-half elems
        const int k = tid - 128;
        const float pos = (float)segpos[t];
        const size_t base = row + 2048 + (size_t)(k >> 3) * 128 + (k & 7) * 8;
        short8 aF = *(const short8*)(Q0 + base);
        short8 bF = *(const short8*)(qkvb + base);
        short8 aS = *(const short8*)(Q0 + base + 64);
        short8 bS = *(const short8*)(qkvb + base + 64);
        const bf16* afp = (const bf16*)&aF;
        const bf16* bfp = (const bf16*)&bF;
        const bf16* asp = (const bf16*)&aS;
        const bf16* bsp = (const bf16*)&bS;
        bf16 oF[8], oS[8];
#pragma unroll
        for (int j = 0; j < 8; ++j) {
            const int hp = (k & 7) * 8 + j;
            float first  = b2f(afp[j]) + b2f(bfp[j]);
            float second = b2f(asp[j]) + b2f(bsp[j]);
            float ang = pos * __expf(-(float)hp * (1.0f / 64.0f) * LN_BASE);
            float sv, cv; __sincosf(ang, &sv, &cv);
            oF[j] = f2b(first * cv - second * sv);
            oS[j] = f2b(second * cv + first * sv);
        }
        *(short8*)(qkvb + base)      = *(const short8*)oF;
        *(short8*)(qkvb + base + 64) = *(const short8*)oS;
    }
}

// ---------------------------------------------------------------------------
// Split-K MFMA GEMM: grid.z selects K-half; writes fp32 partials.
// 128x128 tile (m97 structure); Ndim=2048, K-half = 1024.
// ---------------------------------------------------------------------------
__global__ __launch_bounds__(256) void mfma_gemm_splitk_k(
    const bf16* __restrict__ A, const bf16* __restrict__ BT,
    float* __restrict__ P0, float* __restrict__ P1)
{
    __shared__ alignas(16) bf16 As[128 * 32];
    __shared__ alignas(16) bf16 Bs[128 * 32];

    const int tid  = threadIdx.x;
    const int lane = tid & 63;
    const int wave = tid >> 6;
    const int lo   = lane & 15;
    const int quad = lane >> 4;
    const int row0 = blockIdx.x * 128;
    const int col0 = blockIdx.y * 128;
    const int kbeg = blockIdx.z * 1024;
    float* __restrict__ P = blockIdx.z ? P1 : P0;
    const int wm = (wave >> 1) * 64;
    const int wn = (wave & 1) * 64;

    const int lrow = lane >> 2;
    const int lcol = ((lane & 3) ^ ((lane >> 3) & 3)) * 8;
    const int swk  = (quad ^ ((lo >> 1) & 3)) * 8;

    floatx4 acc[4][4];
#pragma unroll
    for (int i = 0; i < 4; ++i)
#pragma unroll
        for (int j = 0; j < 4; ++j) acc[i][j] = (floatx4){0.f, 0.f, 0.f, 0.f};

    for (int k0 = kbeg; k0 < kbeg + 1024; k0 += 32) {
        __syncthreads();
#pragma unroll
        for (int i = 0; i < 2; ++i) {
            const int trow = wave * 32 + i * 16 + lrow;
            const bf16* ga = A  + (size_t)(row0 + trow) * 2048 + k0 + lcol;
            const bf16* gb = BT + (size_t)(col0 + trow) * 2048 + k0 + lcol;
            __builtin_amdgcn_global_load_lds(
                (const __attribute__((address_space(1))) void*)ga,
                (__attribute__((address_space(3))) void*)(As + (wave * 2 + i) * 512),
                16, 0, 0);
            __builtin_amdgcn_global_load_lds(
                (const __attribute__((address_space(1))) void*)gb,
                (__attribute__((address_space(3))) void*)(Bs + (wave * 2 + i) * 512),
                16, 0, 0);
        }
        __syncthreads();

        short8 af[4], bfr[4];
#pragma unroll
        for (int mt = 0; mt < 4; ++mt)
            af[mt] = *(const short8*)&As[(wm + mt * 16 + lo) * 32 + swk];
#pragma unroll
        for (int nt = 0; nt < 4; ++nt)
            bfr[nt] = *(const short8*)&Bs[(wn + nt * 16 + lo) * 32 + swk];
#pragma unroll
        for (int mt = 0; mt < 4; ++mt)
#pragma unroll
            for (int nt = 0; nt < 4; ++nt)
                acc[mt][nt] = __builtin_amdgcn_mfma_f32_16x16x32_bf16(
                    af[mt], bfr[nt], acc[mt][nt], 0, 0, 0);
    }

#pragma unroll
    for (int mt = 0; mt < 4; ++mt)
#pragma unroll
        for (int nt = 0; nt < 4; ++nt)
#pragma unroll
            for (int r = 0; r < 4; ++r) {
                int rr = row0 + wm + mt * 16 + quad * 4 + r;
                int cc = col0 + wn + nt * 16 + lo;
                P[(size_t)rr * 2048 + cc] = acc[mt][nt][r];
            }
}

// ---------------------------------------------------------------------------
// out = P0 + P1 (float4, 4 elems/thread)
// ---------------------------------------------------------------------------
__global__ __launch_bounds__(256) void add_out_k(
    const float* __restrict__ P0, const float* __restrict__ P1,
    float* __restrict__ out)
{
    const size_t i = ((size_t)blockIdx.x * 256 + threadIdx.x) * 4;
    float4 a = *(const float4*)(P0 + i);
    float4 b = *(const float4*)(P1 + i);
    float4 o = {a.x + b.x, a.y + b.y, a.z + b.z, a.w + b.w};
    *(float4*)(out + i) = o;
}

// ---------------------------------------------------------------------------
// Flash MFMA attention, fixed-m softmax (softcap bounds logits to ±50).
// Round-5 GQA fusion: heads 2kh,2kh+1 share K/V -> one 512-thread block
// stages the shared window ONCE and computes both heads.
//   waves 0-3: head 2kh,   rows (wave&3)*16..+16; stage K (tid<256)
//   waves 4-7: head 2kh+1, rows (wave&3)*16..+16; stage V (tid>=256)
// Per-wave math body identical to the round-1 verified kernel.
// Grid 256 = 1 block/CU; staged chunks halve (13056 -> 6528); compute per
// barrier interval doubles -> prefetch covers HBM latency.
// ---------------------------------------------------------------------------
__global__ __launch_bounds__(512) void attn_k(
    const bf16* __restrict__ qkvb, const int* __restrict__ segpos,
    bf16* __restrict__ ebuf)
{
    __shared__ alignas(16) bf16 Ks[2][32][136];
    __shared__ alignas(16) bf16 Vt[2][128][40];
    __shared__ alignas(16) bf16 Ps[8][16][40];

    const int id  = blockIdx.x;
    const int bxi = id & 31;
    const int kh  = id >> 5;
    const int t0  = bxi * 64;
    const int tid  = threadIdx.x;
    const int lane = tid & 63;
    const int wave = tid >> 6;              // 0..7
    const int lo   = lane & 15;
    const int quad = lane >> 4;
    const int n    = kh * 2 + (wave >> 2);  // this wave's head
    const int twlo = t0 + (wave & 3) * 16;  // this wave's 16 query rows

    short8 qf[4];
    {
        const int tq = twlo + lo;
        const float pos = (float)segpos[tq];
        const bf16* qp = qkvb + (size_t)tq * 4096 + n * 128;
        float qv[4][8];
#pragma unroll
        for (int kc = 0; kc < 4; ++kc) {
            short8 raw = *(const short8*)(qp + kc * 32 + quad * 8);
            const bf16* rb = (const bf16*)&raw;
#pragma unroll
            for (int j = 0; j < 8; ++j) qv[kc][j] = b2f(rb[j]);
        }
#pragma unroll
        for (int kc = 0; kc < 2; ++kc)
#pragma unroll
            for (int j = 0; j < 8; ++j) {
                int hp = kc * 32 + quad * 8 + j;
                float ang = pos * __expf(-(float)hp * (1.0f / 64.0f) * LN_BASE);
                float sv, cv; __sincosf(ang, &sv, &cv);
                float first = qv[kc][j], second = qv[kc + 2][j];
                qv[kc][j]     = (first * cv - second * sv) * Q_SCALE;
                qv[kc + 2][j] = (second * cv + first * sv) * Q_SCALE;
            }
#pragma unroll
        for (int kc = 0; kc < 4; ++kc) {
            bf16 o[8];
#pragma unroll
            for (int j = 0; j < 8; ++j) o[j] = f2b(qv[kc][j]);
            qf[kc] = *(const short8*)o;
        }
    }

    floatx4 O[8];
#pragma unroll
    for (int i = 0; i < 8; ++i) O[i] = (floatx4){0.f, 0.f, 0.f, 0.f};
    float l_acc[4] = {0.f, 0.f, 0.f, 0.f};

    // staging roles (wave-uniform): tid<256 -> K, tid>=256 -> V
    const bool isK  = (tid < 256);
    const int  st   = tid & 255;
    const int key_a = st >> 3,       hd_a = (st & 7) * 16;
    const int kp2   = (st & 15) * 2, hd_b = (st >> 4) * 8;

    const int s_start = (t0 > 1023) ? (t0 - 1024) : 0;
    const int nch = (t0 + 63 - s_start) / 32 + 1;

    const bf16* kg = qkvb + 2048 + kh * 128;
    const bf16* vg = qkvb + 3072 + kh * 128;

    short8 r0, r1;
    if (isK) {
        r0 = *(const short8*)(kg + (size_t)(s_start + key_a) * 4096 + hd_a);
        r1 = *(const short8*)(kg + (size_t)(s_start + key_a) * 4096 + hd_a + 8);
    } else {
        r0 = *(const short8*)(vg + (size_t)(s_start + kp2) * 4096 + hd_b);
        r1 = *(const short8*)(vg + (size_t)(s_start + kp2 + 1) * 4096 + hd_b);
    }

    for (int c = 0; c < nch; ++c) {
        const int base = s_start + c * 32;
        const int buf = c & 1;

        if (isK) {
            *(short8*)&Ks[buf][key_a][hd_a]     = r0;
            *(short8*)&Ks[buf][key_a][hd_a + 8] = r1;
        } else {
#pragma unroll
            for (int i = 0; i < 8; ++i) {
                unsigned pk = (unsigned)(unsigned short)r0[i] |
                              ((unsigned)(unsigned short)r1[i] << 16);
                *(unsigned*)&Vt[buf][hd_b + i][kp2] = pk;
            }
        }
        if (c + 1 < nch) {
            const int nb = base + 32;
            if (isK) {
                r0 = *(const short8*)(kg + (size_t)(nb + key_a) * 4096 + hd_a);
                r1 = *(const short8*)(kg + (size_t)(nb + key_a) * 4096 + hd_a + 8);
            } else {
                r0 = *(const short8*)(vg + (size_t)(nb + kp2) * 4096 + hd_b);
                r1 = *(const short8*)(vg + (size_t)(nb + kp2 + 1) * 4096 + hd_b);
            }
        }
        __syncthreads();

        const int dbase = twlo - base;
        if (dbase >= -15 && dbase <= 1054) {
            floatx4 S0 = (floatx4){0.f, 0.f, 0.f, 0.f};
            floatx4 S1 = (floatx4){0.f, 0.f, 0.f, 0.f};
#pragma unroll
            for (int kc = 0; kc < 4; ++kc) {
                short8 b0 = *(const short8*)&Ks[buf][lo][kc * 32 + quad * 8];
                short8 b1 = *(const short8*)&Ks[buf][16 + lo][kc * 32 + quad * 8];
                S0 = __builtin_amdgcn_mfma_f32_16x16x32_bf16(qf[kc], b0, S0, 0, 0, 0);
                S1 = __builtin_amdgcn_mfma_f32_16x16x32_bf16(qf[kc], b1, S1, 0, 0, 0);
            }
            short8 vfrag[8];
#pragma unroll
            for (int nt = 0; nt < 8; ++nt)
                vfrag[nt] = *(const short8*)&Vt[buf][nt * 16 + lo][quad * 8];

            const bool need_mask = !(dbase >= 31 && dbase <= 1008);
            const int dq = dbase + quad * 4 - lo;
            float lg[2][4];
#pragma unroll
            for (int tau = 0; tau < 2; ++tau) {
#pragma unroll
                for (int r = 0; r < 4; ++r) {
                    float sv = (tau == 0) ? S0[r] : S1[r];
                    float ax = fabsf(sv) * (2.0f / SOFT_CAP);
                    float e2 = __expf(-ax);
                    float th = (1.0f - e2) * __builtin_amdgcn_rcpf(1.0f + e2);
                    float l  = copysignf(SOFT_CAP * th, sv);
                    float p  = __expf(l);
                    if (need_mask) {
                        int d = dq + r - tau * 16;
                        if ((unsigned)d > 1023u) p = 0.f;
                    }
                    lg[tau][r] = p;
                }
            }
#pragma unroll
            for (int r = 0; r < 4; ++r) l_acc[r] += lg[0][r] + lg[1][r];

#pragma unroll
            for (int tau = 0; tau < 2; ++tau)
#pragma unroll
                for (int r = 0; r < 4; ++r)
                    Ps[wave][quad * 4 + r][tau * 16 + lo] = f2b(lg[tau][r]);

            short8 pfrag = *(const short8*)&Ps[wave][lo][quad * 8];
#pragma unroll
            for (int nt = 0; nt < 8; ++nt)
                O[nt] = __builtin_amdgcn_mfma_f32_16x16x32_bf16(pfrag, vfrag[nt], O[nt], 0, 0, 0);
        }
    }

#pragma unroll
    for (int xm = 1; xm < 16; xm <<= 1)
#pragma unroll
        for (int r = 0; r < 4; ++r) l_acc[r] += __shfl_xor(l_acc[r], xm, 64);
    float invl[4];
#pragma unroll
    for (int r = 0; r < 4; ++r) invl[r] = 1.0f / l_acc[r];

#pragma unroll
    for (int nt = 0; nt < 8; ++nt)
#pragma unroll
        for (int r = 0; r < 4; ++r) {
            int t = twlo + quad * 4 + r;
            ebuf[(size_t)t * 2048 + n * 128 + nt * 16 + lo] = f2b(O[nt][r] * invl[r]);
        }
}

// ---------------------------------------------------------------------------
extern "C" void kernel_launch(void* const* d_in, const int* in_sizes, int n_in,
                              void* d_out, int out_size, void* d_ws, size_t ws_size,
                              hipStream_t stream)
{
    const float* x   = (const float*)d_in[0];
    const int*  segp = (const int*)d_in[1];
    // d_in[2] = attn_mask (bool) -- redundant with causal+window predicate, ignored
    const float* qk  = (const float*)d_in[3];
    const float* kvk = (const float*)d_in[4];
    const float* ok  = (const float*)d_in[5];

    // Workspace (~50 MB): xb(0..8, aliased by ebuf) | WT_qkv(8..24.8) | WT_out(24.8..33.2) | qkvb(33.2..50)
    // QKV split-K partial Q0 aliases d_out (16.8 MB, written last by add_out_k).
    // After attn_k: WT_qkv and qkvb are dead -> reused as fp32 split-K partials for out-proj.
    bf16* xb     = (bf16*)d_ws;
    bf16* ebuf   = xb;
    bf16* WT_qkv = xb + (size_t)4 * 1024 * 1024;
    bf16* WT_out = WT_qkv + (size_t)8 * 1024 * 1024;
    bf16* qkvb   = WT_out + (size_t)4 * 1024 * 1024;
    bf16* Q0     = (bf16*)d_out;           // qkv split-K partial (z=0)
    float* P0    = (float*)WT_qkv;
    float* P1    = (float*)qkvb;
    float* outp  = (float*)d_out;

    prep_k<<<dim3(14336), dim3(256), 0, stream>>>(x, qk, kvk, ok, xb, WT_qkv, WT_out);
    gemm_qkv_8ph_k<<<dim3(128, 2), dim3(512), 0, stream>>>(xb, WT_qkv, Q0, qkvb);
    qkv_addrope_k<<<dim3(T_DIM), dim3(256), 0, stream>>>(Q0, qkvb, segp);
    attn_k<<<dim3(256), dim3(512), 0, stream>>>(qkvb, segp, ebuf);
    mfma_gemm_splitk_k<<<dim3(16, 16, 2), dim3(256), 0, stream>>>(
        ebuf, WT_out, P0, P1);
    add_out_k<<<dim3(4096), dim3(256), 0, stream>>>(P0, P1, outp);
}

// Round 7
// 251.371 us; speedup vs baseline: 1.1012x; 1.0007x over previous
//
#include <hip/hip_runtime.h>
#include <hip/hip_bf16.h>
#include <math.h>

// Problem constants (B=1)
#define T_DIM 2048
#define D_DIM 2048
#define N_HEADS 16
#define K_HEADS 8
#define H_DIM 128
#define WINDOW_SZ 1024
#define SOFT_CAP 50.0f
#define Q_SCALE 0.08838834764831845f   // 1/sqrt(128)
#define LN_BASE 9.210340371976184f     // ln(10000)

typedef __hip_bfloat16 bf16;
typedef __attribute__((ext_vector_type(8))) short short8;
typedef __attribute__((ext_vector_type(4))) float floatx4;

static __device__ __forceinline__ bf16 f2b(float v) { return __float2bfloat16(v); }
static __device__ __forceinline__ float b2f(bf16 v) { return __bfloat162float(v); }

// ---------------------------------------------------------------------------
// Fused prep: 1D grid.
//   [0, 8192)     : qkv weight transpose (32 matrices, 2048x128 -> rows z*128 of WT_qkv)
//   [8192, 12288) : out weight transpose (16 matrices, 128x2048 -> cols z*128 of WT_out)
//   [12288,14336) : x fp32 -> bf16 copy
// ---------------------------------------------------------------------------
__global__ __launch_bounds__(256) void prep_k(
    const float* __restrict__ x, const float* __restrict__ qk,
    const float* __restrict__ kvk, const float* __restrict__ ok,
    bf16* __restrict__ xb, bf16* __restrict__ WT_qkv, bf16* __restrict__ WT_out)
{
    __shared__ float tile[32][33];
    const int b = blockIdx.x;
    const int tid = threadIdx.x;
    const int tx = tid & 31, ty = tid >> 5;

    if (b < 8192) {
        const int z = b >> 8, rem = b & 255;
        const int c0 = (rem & 3) * 32;        // over H (128)
        const int r0 = (rem >> 2) * 32;       // over D (2048)
        const float* src = (z < 16) ? qk + (size_t)z * D_DIM * H_DIM
                                    : kvk + (size_t)(z - 16) * D_DIM * H_DIM;
        bf16* dst = WT_qkv + (size_t)z * 128 * 2048;
#pragma unroll
        for (int i = 0; i < 4; ++i)
            tile[ty + i * 8][tx] = src[(size_t)(r0 + ty + i * 8) * H_DIM + c0 + tx];
        __syncthreads();
#pragma unroll
        for (int i = 0; i < 4; ++i)
            dst[(size_t)(c0 + ty + i * 8) * 2048 + r0 + tx] = f2b(tile[tx][ty + i * 8]);
    } else if (b < 12288) {
        const int b2 = b - 8192;
        const int z = b2 >> 8, rem = b2 & 255;
        const int c0 = (rem & 63) * 32;       // over D (2048)
        const int r0 = (rem >> 6) * 32;       // over H (128)
        const float* src = ok + (size_t)z * H_DIM * D_DIM;
        bf16* dst = WT_out + (size_t)z * H_DIM;
#pragma unroll
        for (int i = 0; i < 4; ++i)
            tile[ty + i * 8][tx] = src[(size_t)(r0 + ty + i * 8) * D_DIM + c0 + tx];
        __syncthreads();
#pragma unroll
        for (int i = 0; i < 4; ++i)
            dst[(size_t)(c0 + ty + i * 8) * 2048 + r0 + tx] = f2b(tile[tx][ty + i * 8]);
    } else {
        const size_t i = ((size_t)(b - 12288) * 256 + tid) * 8;
        float4 a = *(const float4*)(x + i);
        float4 bb = *(const float4*)(x + i + 4);
        bf16 o[8] = {f2b(a.x), f2b(a.y), f2b(a.z), f2b(a.w),
                     f2b(bb.x), f2b(bb.y), f2b(bb.z), f2b(bb.w)};
        *(short8*)(xb + i) = *(const short8*)o;
    }
}

// ---------------------------------------------------------------------------
// 256x256 8-phase GEMM (T2+T3+T4+T5), QKV projection, SPLIT-K z=2 (verified r2).
// ---------------------------------------------------------------------------
static __device__ __forceinline__ void stageT(const bf16* __restrict__ gsrc,
                                              bf16* ldst, int h, int r, int kt)
{
    __builtin_amdgcn_global_load_lds(
        (const __attribute__((address_space(1))) void*)
            (gsrc + (size_t)((h * 128 + r * 64) * 2048 + kt * 64)),
        (__attribute__((address_space(3))) void*)(ldst + h * 8192 + r * 4096),
        16, 0, 0);
}

template <int MTB>
static __device__ __forceinline__ void readA4(short8 (&dst)[4][2], const bf16* base,
                                              int rlo, const int (&cs)[2])
{
#pragma unroll
    for (int mt = 0; mt < 4; ++mt)
#pragma unroll
        for (int ks = 0; ks < 2; ++ks)
            dst[mt][ks] = *(const short8*)&base[(rlo + (MTB + mt) * 16) * 64 + cs[ks]];
}

template <int NTB>
static __device__ __forceinline__ void readB2(short8 (&dst)[2][2], const bf16* base,
                                              int rlo, const int (&cs)[2])
{
#pragma unroll
    for (int n2 = 0; n2 < 2; ++n2)
#pragma unroll
        for (int ks = 0; ks < 2; ++ks)
            dst[n2][ks] = *(const short8*)&base[(rlo + (NTB + n2) * 16) * 64 + cs[ks]];
}

template <int MB, int NB>
static __device__ __forceinline__ void mfma16(floatx4 (&acc)[8][4],
                                              const short8 (&af)[4][2],
                                              const short8 (&bf)[2][2])
{
#pragma unroll
    for (int mt = 0; mt < 4; ++mt)
#pragma unroll
        for (int n2 = 0; n2 < 2; ++n2) {
            acc[MB + mt][NB + n2] = __builtin_amdgcn_mfma_f32_16x16x32_bf16(
                af[mt][0], bf[n2][0], acc[MB + mt][NB + n2], 0, 0, 0);
            acc[MB + mt][NB + n2] = __builtin_amdgcn_mfma_f32_16x16x32_bf16(
                af[mt][1], bf[n2][1], acc[MB + mt][NB + n2], 0, 0, 0);
        }
}

__global__ __launch_bounds__(512, 2) void gemm_qkv_8ph_k(
    const bf16* __restrict__ A, const bf16* __restrict__ BT,
    bf16* __restrict__ P0, bf16* __restrict__ P1)
{
    __shared__ alignas(16) bf16 lds[2][2][16384];   // [buf][A/B][256*64]

    const int tid  = threadIdx.x;
    const int lane = tid & 63;
    const int wave = tid >> 6;
    const int lo   = lane & 15;
    const int quad = lane >> 4;

    const int wg   = blockIdx.x;
    const int row0 = (wg & 7) * 256;
    const int col0 = (wg >> 3) * 256;
    const int kb   = blockIdx.y * 16;            // K-tile base (z * 1024 elems)
    bf16* __restrict__ Pd = blockIdx.y ? P1 : P0;

    const int wm   = (wave >> 2) * 128;   // WARPS_M = 2
    const int wn   = (wave & 3) * 64;     // WARPS_N = 4
    const int wmlo = wm + lo, wnlo = wn + lo;

    const int r_y   = wave * 8 + (lane >> 3);                   // 0..63
    const int c_src = ((lane & 7) ^ ((lane >> 3) & 7)) * 8;     // elements
    const bf16* pA = A  + (size_t)(row0 + r_y) * 2048 + c_src;
    const bf16* pB = BT + (size_t)(col0 + r_y) * 2048 + c_src;

    bf16* ldsA0 = &lds[0][0][0] + wave * 512;
    bf16* ldsB0 = &lds[0][1][0] + wave * 512;
    bf16* ldsA1 = &lds[1][0][0] + wave * 512;
    bf16* ldsB1 = &lds[1][1][0] + wave * 512;

    const int cs[2] = { (quad * 8) ^ ((lo & 7) << 3),
                        (32 + quad * 8) ^ ((lo & 7) << 3) };

    floatx4 acc[8][4];
#pragma unroll
    for (int i = 0; i < 8; ++i)
#pragma unroll
        for (int j = 0; j < 4; ++j) acc[i][j] = (floatx4){0.f, 0.f, 0.f, 0.f};

    stageT(pA, ldsA0, 0, 0, kb); stageT(pA, ldsA0, 0, 1, kb);
    stageT(pA, ldsA0, 1, 0, kb); stageT(pA, ldsA0, 1, 1, kb);
    stageT(pB, ldsB0, 0, 0, kb); stageT(pB, ldsB0, 0, 1, kb);
    stageT(pB, ldsB0, 1, 0, kb); stageT(pB, ldsB0, 1, 1, kb);
    stageT(pA, ldsA1, 0, 0, kb + 1); stageT(pA, ldsA1, 0, 1, kb + 1);
    stageT(pA, ldsA1, 1, 0, kb + 1); stageT(pA, ldsA1, 1, 1, kb + 1);
    stageT(pB, ldsB1, 0, 0, kb + 1); stageT(pB, ldsB1, 0, 1, kb + 1);
    asm volatile("s_waitcnt vmcnt(6)" ::: "memory");   // tile kb fully landed
    __builtin_amdgcn_s_barrier();

    short8 aF[4][2], a2F[4][2], bF[2][2], b2F[2][2];

#pragma unroll 1
    for (int i = 0; i < 8; ++i) {
        const int tb1  = kb + 2 * i + 1;
        const int lt0  = (2 * i + 2 < 16) ? 2 * i + 2 : 15;
        const int lt1  = (2 * i + 3 < 16) ? 2 * i + 3 : 15;
        const int tnx0 = kb + lt0;
        const int tnx1 = kb + lt1;

        // ======== group 0: compute K-tile kb+2i from buf0 ========
        readA4<0>(aF, &lds[0][0][0], wmlo, cs);
        readB2<0>(bF, &lds[0][1][0], wnlo, cs);
        stageT(pB, ldsB1, 1, 0, tb1); stageT(pB, ldsB1, 1, 1, tb1);
        __builtin_amdgcn_s_barrier();
        __builtin_amdgcn_s_setprio(1); mfma16<0, 0>(acc, aF, bF);   __builtin_amdgcn_s_setprio(0);
        __builtin_amdgcn_s_barrier();
        readA4<4>(a2F, &lds[0][0][0], wmlo, cs);
        readB2<2>(b2F, &lds[0][1][0], wnlo, cs);
        __builtin_amdgcn_s_barrier();
        __builtin_amdgcn_s_setprio(1); mfma16<4, 2>(acc, a2F, b2F); __builtin_amdgcn_s_setprio(0);
        __builtin_amdgcn_s_barrier();
        stageT(pA, ldsA0, 0, 0, tnx0); stageT(pA, ldsA0, 0, 1, tnx0);
        stageT(pA, ldsA0, 1, 0, tnx0); stageT(pA, ldsA0, 1, 1, tnx0);
        __builtin_amdgcn_s_barrier();
        __builtin_amdgcn_s_setprio(1); mfma16<0, 2>(acc, aF, b2F);  __builtin_amdgcn_s_setprio(0);
        __builtin_amdgcn_s_barrier();
        stageT(pB, ldsB0, 0, 0, tnx0); stageT(pB, ldsB0, 0, 1, tnx0);
        asm volatile("s_waitcnt vmcnt(6)" ::: "memory");
        __builtin_amdgcn_s_barrier();
        __builtin_amdgcn_s_setprio(1); mfma16<4, 0>(acc, a2F, bF);  __builtin_amdgcn_s_setprio(0);
        __builtin_amdgcn_s_barrier();

        // ======== group 1: compute K-tile kb+2i+1 from buf1 ========
        readA4<0>(aF, &lds[1][0][0], wmlo, cs);
        readB2<0>(bF, &lds[1][1][0], wnlo, cs);
        stageT(pB, ldsB0, 1, 0, tnx0); stageT(pB, ldsB0, 1, 1, tnx0);
        __builtin_amdgcn_s_barrier();
        __builtin_amdgcn_s_setprio(1); mfma16<0, 0>(acc, aF, bF);   __builtin_amdgcn_s_setprio(0);
        __builtin_amdgcn_s_barrier();
        readA4<4>(a2F, &lds[1][0][0], wmlo, cs);
        readB2<2>(b2F, &lds[1][1][0], wnlo, cs);
        __builtin_amdgcn_s_barrier();
        __builtin_amdgcn_s_setprio(1); mfma16<4, 2>(acc, a2F, b2F); __builtin_amdgcn_s_setprio(0);
        __builtin_amdgcn_s_barrier();
        stageT(pA, ldsA1, 0, 0, tnx1); stageT(pA, ldsA1, 0, 1, tnx1);
        stageT(pA, ldsA1, 1, 0, tnx1); stageT(pA, ldsA1, 1, 1, tnx1);
        __builtin_amdgcn_s_barrier();
        __builtin_amdgcn_s_setprio(1); mfma16<0, 2>(acc, aF, b2F);  __builtin_amdgcn_s_setprio(0);
        __builtin_amdgcn_s_barrier();
        stageT(pB, ldsB1, 0, 0, tnx1); stageT(pB, ldsB1, 0, 1, tnx1);
        asm volatile("s_waitcnt vmcnt(6)" ::: "memory");
        __builtin_amdgcn_s_barrier();
        __builtin_amdgcn_s_setprio(1); mfma16<4, 0>(acc, a2F, bF);  __builtin_amdgcn_s_setprio(0);
        __builtin_amdgcn_s_barrier();
    }

#pragma unroll
    for (int mt = 0; mt < 8; ++mt)
#pragma unroll
        for (int nt = 0; nt < 4; ++nt)
#pragma unroll
            for (int r = 0; r < 4; ++r) {
                int rr = row0 + wm + mt * 16 + quad * 4 + r;
                int cc = col0 + wn + nt * 16 + lo;
                Pd[(size_t)rr * 4096 + cc] = f2b(acc[mt][nt][r]);
            }
}

// ---------------------------------------------------------------------------
// Fused: qkvb = Q0 + qkvb, then RoPE on the K region (verified r5).
// ---------------------------------------------------------------------------
__global__ __launch_bounds__(256) void qkv_addrope_k(
    const bf16* __restrict__ Q0, bf16* __restrict__ qkvb,
    const int* __restrict__ segpos)
{
    const int t = blockIdx.x;
    const int tid = threadIdx.x;
    const size_t row = (size_t)t * 4096;

    if (tid < 128 || tid >= 192) {
        // Q region (threads 0..127 -> 2048 elems) / V region (192..255 -> 1024)
        const size_t i = (tid < 128) ? row + (size_t)tid * 16
                                     : row + 3072 + (size_t)(tid - 192) * 16;
#pragma unroll
        for (int h = 0; h < 2; ++h) {
            short8 a = *(const short8*)(Q0 + i + h * 8);
            short8 b = *(const short8*)(qkvb + i + h * 8);
            const bf16* ap = (const bf16*)&a;
            const bf16* bp = (const bf16*)&b;
            bf16 o[8];
#pragma unroll
            for (int j = 0; j < 8; ++j) o[j] = f2b(b2f(ap[j]) + b2f(bp[j]));
            *(short8*)(qkvb + i + h * 8) = *(const short8*)o;
        }
    } else {
        // K region: 64 threads, each owns 8 first-half + 8 second-half elems
        const int k = tid - 128;
        const float pos = (float)segpos[t];
        const size_t base = row + 2048 + (size_t)(k >> 3) * 128 + (k & 7) * 8;
        short8 aF = *(const short8*)(Q0 + base);
        short8 bF = *(const short8*)(qkvb + base);
        short8 aS = *(const short8*)(Q0 + base + 64);
        short8 bS = *(const short8*)(qkvb + base + 64);
        const bf16* afp = (const bf16*)&aF;
        const bf16* bfp = (const bf16*)&bF;
        const bf16* asp = (const bf16*)&aS;
        const bf16* bsp = (const bf16*)&bS;
        bf16 oF[8], oS[8];
#pragma unroll
        for (int j = 0; j < 8; ++j) {
            const int hp = (k & 7) * 8 + j;
            float first  = b2f(afp[j]) + b2f(bfp[j]);
            float second = b2f(asp[j]) + b2f(bsp[j]);
            float ang = pos * __expf(-(float)hp * (1.0f / 64.0f) * LN_BASE);
            float sv, cv; __sincosf(ang, &sv, &cv);
            oF[j] = f2b(first * cv - second * sv);
            oS[j] = f2b(second * cv + first * sv);
        }
        *(short8*)(qkvb + base)      = *(const short8*)oF;
        *(short8*)(qkvb + base + 64) = *(const short8*)oS;
    }
}

// ---------------------------------------------------------------------------
// Split-K MFMA GEMM: grid.z selects K-half; writes fp32 partials.
// 128x128 tile (m97 structure); Ndim=2048, K-half = 1024.
// ---------------------------------------------------------------------------
__global__ __launch_bounds__(256) void mfma_gemm_splitk_k(
    const bf16* __restrict__ A, const bf16* __restrict__ BT,
    float* __restrict__ P0, float* __restrict__ P1)
{
    __shared__ alignas(16) bf16 As[128 * 32];
    __shared__ alignas(16) bf16 Bs[128 * 32];

    const int tid  = threadIdx.x;
    const int lane = tid & 63;
    const int wave = tid >> 6;
    const int lo   = lane & 15;
    const int quad = lane >> 4;
    const int row0 = blockIdx.x * 128;
    const int col0 = blockIdx.y * 128;
    const int kbeg = blockIdx.z * 1024;
    float* __restrict__ P = blockIdx.z ? P1 : P0;
    const int wm = (wave >> 1) * 64;
    const int wn = (wave & 1) * 64;

    const int lrow = lane >> 2;
    const int lcol = ((lane & 3) ^ ((lane >> 3) & 3)) * 8;
    const int swk  = (quad ^ ((lo >> 1) & 3)) * 8;

    floatx4 acc[4][4];
#pragma unroll
    for (int i = 0; i < 4; ++i)
#pragma unroll
        for (int j = 0; j < 4; ++j) acc[i][j] = (floatx4){0.f, 0.f, 0.f, 0.f};

    for (int k0 = kbeg; k0 < kbeg + 1024; k0 += 32) {
        __syncthreads();
#pragma unroll
        for (int i = 0; i < 2; ++i) {
            const int trow = wave * 32 + i * 16 + lrow;
            const bf16* ga = A  + (size_t)(row0 + trow) * 2048 + k0 + lcol;
            const bf16* gb = BT + (size_t)(col0 + trow) * 2048 + k0 + lcol;
            __builtin_amdgcn_global_load_lds(
                (const __attribute__((address_space(1))) void*)ga,
                (__attribute__((address_space(3))) void*)(As + (wave * 2 + i) * 512),
                16, 0, 0);
            __builtin_amdgcn_global_load_lds(
                (const __attribute__((address_space(1))) void*)gb,
                (__attribute__((address_space(3))) void*)(Bs + (wave * 2 + i) * 512),
                16, 0, 0);
        }
        __syncthreads();

        short8 af[4], bfr[4];
#pragma unroll
        for (int mt = 0; mt < 4; ++mt)
            af[mt] = *(const short8*)&As[(wm + mt * 16 + lo) * 32 + swk];
#pragma unroll
        for (int nt = 0; nt < 4; ++nt)
            bfr[nt] = *(const short8*)&Bs[(wn + nt * 16 + lo) * 32 + swk];
#pragma unroll
        for (int mt = 0; mt < 4; ++mt)
#pragma unroll
            for (int nt = 0; nt < 4; ++nt)
                acc[mt][nt] = __builtin_amdgcn_mfma_f32_16x16x32_bf16(
                    af[mt], bfr[nt], acc[mt][nt], 0, 0, 0);
    }

#pragma unroll
    for (int mt = 0; mt < 4; ++mt)
#pragma unroll
        for (int nt = 0; nt < 4; ++nt)
#pragma unroll
            for (int r = 0; r < 4; ++r) {
                int rr = row0 + wm + mt * 16 + quad * 4 + r;
                int cc = col0 + wn + nt * 16 + lo;
                P[(size_t)rr * 2048 + cc] = acc[mt][nt][r];
            }
}

// ---------------------------------------------------------------------------
// out = P0 + P1 (float4, 4 elems/thread)
// ---------------------------------------------------------------------------
__global__ __launch_bounds__(256) void add_out_k(
    const float* __restrict__ P0, const float* __restrict__ P1,
    float* __restrict__ out)
{
    const size_t i = ((size_t)blockIdx.x * 256 + threadIdx.x) * 4;
    float4 a = *(const float4*)(P0 + i);
    float4 b = *(const float4*)(P1 + i);
    float4 o = {a.x + b.x, a.y + b.y, a.z + b.z, a.w + b.w};
    *(float4*)(out + i) = o;
}

// ---------------------------------------------------------------------------
// Flash MFMA attention, fixed-m softmax (softcap bounds logits to ±50).
// Round-6 restructure: TWO HEADS PER WAVE (attn_k is LDS-BW-bound; each
// K/V fragment ds_read now feeds 2 MFMAs -> K/V LDS traffic halves).
// 4 waves x 256 threads; wave w owns q-rows t0+w*16..+16 for BOTH heads
// 2kh, 2kh+1. Staging = round-1 verified 256-thread pattern. RoPE trig
// computed once per lane, applied to both heads' Q.
// Grid 256 = 1 block/CU.
// ---------------------------------------------------------------------------
__global__ __launch_bounds__(256) void attn_k(
    const bf16* __restrict__ qkvb, const int* __restrict__ segpos,
    bf16* __restrict__ ebuf)
{
    __shared__ alignas(16) bf16 Ks[2][32][136];
    __shared__ alignas(16) bf16 Vt[2][128][40];
    __shared__ alignas(16) bf16 Ps[4][2][16][40];

    const int id  = blockIdx.x;
    const int bxi = id & 31;
    const int kh  = id >> 5;
    const int t0  = bxi * 64;
    const int n0  = kh * 2;
    const int tid  = threadIdx.x;
    const int lane = tid & 63;
    const int wave = tid >> 6;          // 0..3
    const int lo   = lane & 15;
    const int quad = lane >> 4;
    const int twlo = t0 + wave * 16;

    short8 qf[2][4];
    {
        const int tq = twlo + lo;
        const float pos = (float)segpos[tq];
        const bf16* qp = qkvb + (size_t)tq * 4096 + n0 * 128;
        float qv[2][4][8];
#pragma unroll
        for (int h = 0; h < 2; ++h)
#pragma unroll
            for (int kc = 0; kc < 4; ++kc) {
                short8 raw = *(const short8*)(qp + h * 128 + kc * 32 + quad * 8);
                const bf16* rb = (const bf16*)&raw;
#pragma unroll
                for (int j = 0; j < 8; ++j) qv[h][kc][j] = b2f(rb[j]);
            }
#pragma unroll
        for (int kc = 0; kc < 2; ++kc)
#pragma unroll
            for (int j = 0; j < 8; ++j) {
                int hp = kc * 32 + quad * 8 + j;
                float ang = pos * __expf(-(float)hp * (1.0f / 64.0f) * LN_BASE);
                float sv, cv; __sincosf(ang, &sv, &cv);
#pragma unroll
                for (int h = 0; h < 2; ++h) {
                    float first = qv[h][kc][j], second = qv[h][kc + 2][j];
                    qv[h][kc][j]     = (first * cv - second * sv) * Q_SCALE;
                    qv[h][kc + 2][j] = (second * cv + first * sv) * Q_SCALE;
                }
            }
#pragma unroll
        for (int h = 0; h < 2; ++h)
#pragma unroll
            for (int kc = 0; kc < 4; ++kc) {
                bf16 o[8];
#pragma unroll
                for (int j = 0; j < 8; ++j) o[j] = f2b(qv[h][kc][j]);
                qf[h][kc] = *(const short8*)o;
            }
    }

    floatx4 O[2][8];
#pragma unroll
    for (int h = 0; h < 2; ++h)
#pragma unroll
        for (int i = 0; i < 8; ++i) O[h][i] = (floatx4){0.f, 0.f, 0.f, 0.f};
    float l_acc[2][4] = {{0.f, 0.f, 0.f, 0.f}, {0.f, 0.f, 0.f, 0.f}};

    const int key_a = tid >> 3,      hd_a = (tid & 7) * 16;
    const int kp2   = (tid & 15) * 2, hd_b = (tid >> 4) * 8;

    const int s_start = (t0 > 1023) ? (t0 - 1024) : 0;
    const int nch = (t0 + 63 - s_start) / 32 + 1;

    const bf16* kg = qkvb + 2048 + kh * 128;
    const bf16* vg = qkvb + 3072 + kh * 128;

    short8 kr0 = *(const short8*)(kg + (size_t)(s_start + key_a) * 4096 + hd_a);
    short8 kr1 = *(const short8*)(kg + (size_t)(s_start + key_a) * 4096 + hd_a + 8);
    short8 vr0 = *(const short8*)(vg + (size_t)(s_start + kp2) * 4096 + hd_b);
    short8 vr1 = *(const short8*)(vg + (size_t)(s_start + kp2 + 1) * 4096 + hd_b);

    for (int c = 0; c < nch; ++c) {
        const int base = s_start + c * 32;
        const int buf = c & 1;

        *(short8*)&Ks[buf][key_a][hd_a]     = kr0;
        *(short8*)&Ks[buf][key_a][hd_a + 8] = kr1;
#pragma unroll
        for (int i = 0; i < 8; ++i) {
            unsigned pk = (unsigned)(unsigned short)vr0[i] |
                          ((unsigned)(unsigned short)vr1[i] << 16);
            *(unsigned*)&Vt[buf][hd_b + i][kp2] = pk;
        }
        if (c + 1 < nch) {
            const int nb = base + 32;
            kr0 = *(const short8*)(kg + (size_t)(nb + key_a) * 4096 + hd_a);
            kr1 = *(const short8*)(kg + (size_t)(nb + key_a) * 4096 + hd_a + 8);
            vr0 = *(const short8*)(vg + (size_t)(nb + kp2) * 4096 + hd_b);
            vr1 = *(const short8*)(vg + (size_t)(nb + kp2 + 1) * 4096 + hd_b);
        }
        __syncthreads();

        const int dbase = twlo - base;
        if (dbase >= -15 && dbase <= 1054) {
            // QK^T for both heads, sharing each K-fragment read
            floatx4 S[2][2];
#pragma unroll
            for (int h = 0; h < 2; ++h)
#pragma unroll
                for (int s = 0; s < 2; ++s) S[h][s] = (floatx4){0.f, 0.f, 0.f, 0.f};
#pragma unroll
            for (int kc = 0; kc < 4; ++kc) {
                short8 b0 = *(const short8*)&Ks[buf][lo][kc * 32 + quad * 8];
                short8 b1 = *(const short8*)&Ks[buf][16 + lo][kc * 32 + quad * 8];
                S[0][0] = __builtin_amdgcn_mfma_f32_16x16x32_bf16(qf[0][kc], b0, S[0][0], 0, 0, 0);
                S[0][1] = __builtin_amdgcn_mfma_f32_16x16x32_bf16(qf[0][kc], b1, S[0][1], 0, 0, 0);
                S[1][0] = __builtin_amdgcn_mfma_f32_16x16x32_bf16(qf[1][kc], b0, S[1][0], 0, 0, 0);
                S[1][1] = __builtin_amdgcn_mfma_f32_16x16x32_bf16(qf[1][kc], b1, S[1][1], 0, 0, 0);
            }
            short8 vfrag[8];
#pragma unroll
            for (int nt = 0; nt < 8; ++nt)
                vfrag[nt] = *(const short8*)&Vt[buf][nt * 16 + lo][quad * 8];

            const bool need_mask = !(dbase >= 31 && dbase <= 1008);
            const int dq = dbase + quad * 4 - lo;
            short8 pfrag[2];
#pragma unroll
            for (int h = 0; h < 2; ++h) {
                float lg[2][4];
#pragma unroll
                for (int tau = 0; tau < 2; ++tau) {
#pragma unroll
                    for (int r = 0; r < 4; ++r) {
                        float sv = S[h][tau][r];
                        float ax = fabsf(sv) * (2.0f / SOFT_CAP);
                        float e2 = __expf(-ax);
                        float th = (1.0f - e2) * __builtin_amdgcn_rcpf(1.0f + e2);
                        float l  = copysignf(SOFT_CAP * th, sv);
                        float p  = __expf(l);
                        if (need_mask) {
                            int d = dq + r - tau * 16;
                            if ((unsigned)d > 1023u) p = 0.f;
                        }
                        lg[tau][r] = p;
                    }
                }
#pragma unroll
                for (int r = 0; r < 4; ++r) l_acc[h][r] += lg[0][r] + lg[1][r];

#pragma unroll
                for (int tau = 0; tau < 2; ++tau)
#pragma unroll
                    for (int r = 0; r < 4; ++r)
                        Ps[wave][h][quad * 4 + r][tau * 16 + lo] = f2b(lg[tau][r]);

                pfrag[h] = *(const short8*)&Ps[wave][h][lo][quad * 8];
            }
            // PV for both heads, sharing each V-fragment read
#pragma unroll
            for (int nt = 0; nt < 8; ++nt) {
                O[0][nt] = __builtin_amdgcn_mfma_f32_16x16x32_bf16(pfrag[0], vfrag[nt], O[0][nt], 0, 0, 0);
                O[1][nt] = __builtin_amdgcn_mfma_f32_16x16x32_bf16(pfrag[1], vfrag[nt], O[1][nt], 0, 0, 0);
            }
        }
    }

#pragma unroll
    for (int h = 0; h < 2; ++h) {
#pragma unroll
        for (int xm = 1; xm < 16; xm <<= 1)
#pragma unroll
            for (int r = 0; r < 4; ++r) l_acc[h][r] += __shfl_xor(l_acc[h][r], xm, 64);
        float invl[4];
#pragma unroll
        for (int r = 0; r < 4; ++r) invl[r] = 1.0f / l_acc[h][r];

#pragma unroll
        for (int nt = 0; nt < 8; ++nt)
#pragma unroll
            for (int r = 0; r < 4; ++r) {
                int t = twlo + quad * 4 + r;
                ebuf[(size_t)t * 2048 + (n0 + h) * 128 + nt * 16 + lo] =
                    f2b(O[h][nt][r] * invl[r]);
            }
    }
}

// ---------------------------------------------------------------------------
extern "C" void kernel_launch(void* const* d_in, const int* in_sizes, int n_in,
                              void* d_out, int out_size, void* d_ws, size_t ws_size,
                              hipStream_t stream)
{
    const float* x   = (const float*)d_in[0];
    const int*  segp = (const int*)d_in[1];
    // d_in[2] = attn_mask (bool) -- redundant with causal+window predicate, ignored
    const float* qk  = (const float*)d_in[3];
    const float* kvk = (const float*)d_in[4];
    const float* ok  = (const float*)d_in[5];

    // Workspace (~50 MB): xb(0..8, aliased by ebuf) | WT_qkv(8..24.8) | WT_out(24.8..33.2) | qkvb(33.2..50)
    // QKV split-K partial Q0 aliases d_out (16.8 MB, written last by add_out_k).
    // After attn_k: WT_qkv and qkvb are dead -> reused as fp32 split-K partials for out-proj.
    bf16* xb     = (bf16*)d_ws;
    bf16* ebuf   = xb;
    bf16* WT_qkv = xb + (size_t)4 * 1024 * 1024;
    bf16* WT_out = WT_qkv + (size_t)8 * 1024 * 1024;
    bf16* qkvb   = WT_out + (size_t)4 * 1024 * 1024;
    bf16* Q0     = (bf16*)d_out;           // qkv split-K partial (z=0)
    float* P0    = (float*)WT_qkv;
    float* P1    = (float*)qkvb;
    float* outp  = (float*)d_out;

    prep_k<<<dim3(14336), dim3(256), 0, stream>>>(x, qk, kvk, ok, xb, WT_qkv, WT_out);
    gemm_qkv_8ph_k<<<dim3(128, 2), dim3(512), 0, stream>>>(xb, WT_qkv, Q0, qkvb);
    qkv_addrope_k<<<dim3(T_DIM), dim3(256), 0, stream>>>(Q0, qkvb, segp);
    attn_k<<<dim3(256), dim3(256), 0, stream>>>(qkvb, segp, ebuf);
    mfma_gemm_splitk_k<<<dim3(16, 16, 2), dim3(256), 0, stream>>>(
        ebuf, WT_out, P0, P1);
    add_out_k<<<dim3(4096), dim3(256), 0, stream>>>(P0, P1, outp);
}

// Round 9
// 249.819 us; speedup vs baseline: 1.1080x; 1.0062x over previous
//
#include <hip/hip_runtime.h>
#include <hip/hip_bf16.h>
#include <math.h>

// Problem constants (B=1)
#define T_DIM 2048
#define D_DIM 2048
#define N_HEADS 16
#define K_HEADS 8
#define H_DIM 128
#define WINDOW_SZ 1024
#define SOFT_CAP 50.0f
#define Q_SCALE 0.08838834764831845f   // 1/sqrt(128)
#define LN_BASE 9.210340371976184f     // ln(10000)

typedef __hip_bfloat16 bf16;
typedef __attribute__((ext_vector_type(8))) short short8;
typedef __attribute__((ext_vector_type(4))) float floatx4;

static __device__ __forceinline__ bf16 f2b(float v) { return __float2bfloat16(v); }
static __device__ __forceinline__ float b2f(bf16 v) { return __bfloat162float(v); }

// ---------------------------------------------------------------------------
// Fused prep: 1D grid.
//   [0, 8192)     : qkv weight transpose (32 matrices, 2048x128 -> rows z*128 of WT_qkv)
//   [8192, 12288) : out weight transpose (16 matrices, 128x2048 -> cols z*128 of WT_out)
//   [12288,14336) : x fp32 -> bf16 copy
// ---------------------------------------------------------------------------
__global__ __launch_bounds__(256) void prep_k(
    const float* __restrict__ x, const float* __restrict__ qk,
    const float* __restrict__ kvk, const float* __restrict__ ok,
    bf16* __restrict__ xb, bf16* __restrict__ WT_qkv, bf16* __restrict__ WT_out)
{
    __shared__ float tile[32][33];
    const int b = blockIdx.x;
    const int tid = threadIdx.x;
    const int tx = tid & 31, ty = tid >> 5;

    if (b < 8192) {
        const int z = b >> 8, rem = b & 255;
        const int c0 = (rem & 3) * 32;        // over H (128)
        const int r0 = (rem >> 2) * 32;       // over D (2048)
        const float* src = (z < 16) ? qk + (size_t)z * D_DIM * H_DIM
                                    : kvk + (size_t)(z - 16) * D_DIM * H_DIM;
        bf16* dst = WT_qkv + (size_t)z * 128 * 2048;
#pragma unroll
        for (int i = 0; i < 4; ++i)
            tile[ty + i * 8][tx] = src[(size_t)(r0 + ty + i * 8) * H_DIM + c0 + tx];
        __syncthreads();
#pragma unroll
        for (int i = 0; i < 4; ++i)
            dst[(size_t)(c0 + ty + i * 8) * 2048 + r0 + tx] = f2b(tile[tx][ty + i * 8]);
    } else if (b < 12288) {
        const int b2 = b - 8192;
        const int z = b2 >> 8, rem = b2 & 255;
        const int c0 = (rem & 63) * 32;       // over D (2048)
        const int r0 = (rem >> 6) * 32;       // over H (128)
        const float* src = ok + (size_t)z * H_DIM * D_DIM;
        bf16* dst = WT_out + (size_t)z * H_DIM;
#pragma unroll
        for (int i = 0; i < 4; ++i)
            tile[ty + i * 8][tx] = src[(size_t)(r0 + ty + i * 8) * D_DIM + c0 + tx];
        __syncthreads();
#pragma unroll
        for (int i = 0; i < 4; ++i)
            dst[(size_t)(c0 + ty + i * 8) * 2048 + r0 + tx] = f2b(tile[tx][ty + i * 8]);
    } else {
        const size_t i = ((size_t)(b - 12288) * 256 + tid) * 8;
        float4 a = *(const float4*)(x + i);
        float4 bb = *(const float4*)(x + i + 4);
        bf16 o[8] = {f2b(a.x), f2b(a.y), f2b(a.z), f2b(a.w),
                     f2b(bb.x), f2b(bb.y), f2b(bb.z), f2b(bb.w)};
        *(short8*)(xb + i) = *(const short8*)o;
    }
}

// ---------------------------------------------------------------------------
// 256x256 8-phase GEMM (T2+T3+T4+T5), QKV projection, SPLIT-K z=2 (verified r2).
// ---------------------------------------------------------------------------
static __device__ __forceinline__ void stageT(const bf16* __restrict__ gsrc,
                                              bf16* ldst, int h, int r, int kt)
{
    __builtin_amdgcn_global_load_lds(
        (const __attribute__((address_space(1))) void*)
            (gsrc + (size_t)((h * 128 + r * 64) * 2048 + kt * 64)),
        (__attribute__((address_space(3))) void*)(ldst + h * 8192 + r * 4096),
        16, 0, 0);
}

template <int MTB>
static __device__ __forceinline__ void readA4(short8 (&dst)[4][2], const bf16* base,
                                              int rlo, const int (&cs)[2])
{
#pragma unroll
    for (int mt = 0; mt < 4; ++mt)
#pragma unroll
        for (int ks = 0; ks < 2; ++ks)
            dst[mt][ks] = *(const short8*)&base[(rlo + (MTB + mt) * 16) * 64 + cs[ks]];
}

template <int NTB>
static __device__ __forceinline__ void readB2(short8 (&dst)[2][2], const bf16* base,
                                              int rlo, const int (&cs)[2])
{
#pragma unroll
    for (int n2 = 0; n2 < 2; ++n2)
#pragma unroll
        for (int ks = 0; ks < 2; ++ks)
            dst[n2][ks] = *(const short8*)&base[(rlo + (NTB + n2) * 16) * 64 + cs[ks]];
}

template <int MB, int NB>
static __device__ __forceinline__ void mfma16(floatx4 (&acc)[8][4],
                                              const short8 (&af)[4][2],
                                              const short8 (&bf)[2][2])
{
#pragma unroll
    for (int mt = 0; mt < 4; ++mt)
#pragma unroll
        for (int n2 = 0; n2 < 2; ++n2) {
            acc[MB + mt][NB + n2] = __builtin_amdgcn_mfma_f32_16x16x32_bf16(
                af[mt][0], bf[n2][0], acc[MB + mt][NB + n2], 0, 0, 0);
            acc[MB + mt][NB + n2] = __builtin_amdgcn_mfma_f32_16x16x32_bf16(
                af[mt][1], bf[n2][1], acc[MB + mt][NB + n2], 0, 0, 0);
        }
}

__global__ __launch_bounds__(512, 2) void gemm_qkv_8ph_k(
    const bf16* __restrict__ A, const bf16* __restrict__ BT,
    bf16* __restrict__ P0, bf16* __restrict__ P1)
{
    __shared__ alignas(16) bf16 lds[2][2][16384];   // [buf][A/B][256*64]

    const int tid  = threadIdx.x;
    const int lane = tid & 63;
    const int wave = tid >> 6;
    const int lo   = lane & 15;
    const int quad = lane >> 4;

    const int wg   = blockIdx.x;
    const int row0 = (wg & 7) * 256;
    const int col0 = (wg >> 3) * 256;
    const int kb   = blockIdx.y * 16;            // K-tile base (z * 1024 elems)
    bf16* __restrict__ Pd = blockIdx.y ? P1 : P0;

    const int wm   = (wave >> 2) * 128;   // WARPS_M = 2
    const int wn   = (wave & 3) * 64;     // WARPS_N = 4
    const int wmlo = wm + lo, wnlo = wn + lo;

    const int r_y   = wave * 8 + (lane >> 3);                   // 0..63
    const int c_src = ((lane & 7) ^ ((lane >> 3) & 7)) * 8;     // elements
    const bf16* pA = A  + (size_t)(row0 + r_y) * 2048 + c_src;
    const bf16* pB = BT + (size_t)(col0 + r_y) * 2048 + c_src;

    bf16* ldsA0 = &lds[0][0][0] + wave * 512;
    bf16* ldsB0 = &lds[0][1][0] + wave * 512;
    bf16* ldsA1 = &lds[1][0][0] + wave * 512;
    bf16* ldsB1 = &lds[1][1][0] + wave * 512;

    const int cs[2] = { (quad * 8) ^ ((lo & 7) << 3),
                        (32 + quad * 8) ^ ((lo & 7) << 3) };

    floatx4 acc[8][4];
#pragma unroll
    for (int i = 0; i < 8; ++i)
#pragma unroll
        for (int j = 0; j < 4; ++j) acc[i][j] = (floatx4){0.f, 0.f, 0.f, 0.f};

    stageT(pA, ldsA0, 0, 0, kb); stageT(pA, ldsA0, 0, 1, kb);
    stageT(pA, ldsA0, 1, 0, kb); stageT(pA, ldsA0, 1, 1, kb);
    stageT(pB, ldsB0, 0, 0, kb); stageT(pB, ldsB0, 0, 1, kb);
    stageT(pB, ldsB0, 1, 0, kb); stageT(pB, ldsB0, 1, 1, kb);
    stageT(pA, ldsA1, 0, 0, kb + 1); stageT(pA, ldsA1, 0, 1, kb + 1);
    stageT(pA, ldsA1, 1, 0, kb + 1); stageT(pA, ldsA1, 1, 1, kb + 1);
    stageT(pB, ldsB1, 0, 0, kb + 1); stageT(pB, ldsB1, 0, 1, kb + 1);
    asm volatile("s_waitcnt vmcnt(6)" ::: "memory");   // tile kb fully landed
    __builtin_amdgcn_s_barrier();

    short8 aF[4][2], a2F[4][2], bF[2][2], b2F[2][2];

#pragma unroll 1
    for (int i = 0; i < 8; ++i) {
        const int tb1  = kb + 2 * i + 1;
        const int lt0  = (2 * i + 2 < 16) ? 2 * i + 2 : 15;
        const int lt1  = (2 * i + 3 < 16) ? 2 * i + 3 : 15;
        const int tnx0 = kb + lt0;
        const int tnx1 = kb + lt1;

        // ======== group 0: compute K-tile kb+2i from buf0 ========
        readA4<0>(aF, &lds[0][0][0], wmlo, cs);
        readB2<0>(bF, &lds[0][1][0], wnlo, cs);
        stageT(pB, ldsB1, 1, 0, tb1); stageT(pB, ldsB1, 1, 1, tb1);
        __builtin_amdgcn_s_barrier();
        __builtin_amdgcn_s_setprio(1); mfma16<0, 0>(acc, aF, bF);   __builtin_amdgcn_s_setprio(0);
        __builtin_amdgcn_s_barrier();
        readA4<4>(a2F, &lds[0][0][0], wmlo, cs);
        readB2<2>(b2F, &lds[0][1][0], wnlo, cs);
        __builtin_amdgcn_s_barrier();
        __builtin_amdgcn_s_setprio(1); mfma16<4, 2>(acc, a2F, b2F); __builtin_amdgcn_s_setprio(0);
        __builtin_amdgcn_s_barrier();
        stageT(pA, ldsA0, 0, 0, tnx0); stageT(pA, ldsA0, 0, 1, tnx0);
        stageT(pA, ldsA0, 1, 0, tnx0); stageT(pA, ldsA0, 1, 1, tnx0);
        __builtin_amdgcn_s_barrier();
        __builtin_amdgcn_s_setprio(1); mfma16<0, 2>(acc, aF, b2F);  __builtin_amdgcn_s_setprio(0);
        __builtin_amdgcn_s_barrier();
        stageT(pB, ldsB0, 0, 0, tnx0); stageT(pB, ldsB0, 0, 1, tnx0);
        asm volatile("s_waitcnt vmcnt(6)" ::: "memory");
        __builtin_amdgcn_s_barrier();
        __builtin_amdgcn_s_setprio(1); mfma16<4, 0>(acc, a2F, bF);  __builtin_amdgcn_s_setprio(0);
        __builtin_amdgcn_s_barrier();

        // ======== group 1: compute K-tile kb+2i+1 from buf1 ========
        readA4<0>(aF, &lds[1][0][0], wmlo, cs);
        readB2<0>(bF, &lds[1][1][0], wnlo, cs);
        stageT(pB, ldsB0, 1, 0, tnx0); stageT(pB, ldsB0, 1, 1, tnx0);
        __builtin_amdgcn_s_barrier();
        __builtin_amdgcn_s_setprio(1); mfma16<0, 0>(acc, aF, bF);   __builtin_amdgcn_s_setprio(0);
        __builtin_amdgcn_s_barrier();
        readA4<4>(a2F, &lds[1][0][0], wmlo, cs);
        readB2<2>(b2F, &lds[1][1][0], wnlo, cs);
        __builtin_amdgcn_s_barrier();
        __builtin_amdgcn_s_setprio(1); mfma16<4, 2>(acc, a2F, b2F); __builtin_amdgcn_s_setprio(0);
        __builtin_amdgcn_s_barrier();
        stageT(pA, ldsA1, 0, 0, tnx1); stageT(pA, ldsA1, 0, 1, tnx1);
        stageT(pA, ldsA1, 1, 0, tnx1); stageT(pA, ldsA1, 1, 1, tnx1);
        __builtin_amdgcn_s_barrier();
        __builtin_amdgcn_s_setprio(1); mfma16<0, 2>(acc, aF, b2F);  __builtin_amdgcn_s_setprio(0);
        __builtin_amdgcn_s_barrier();
        stageT(pB, ldsB1, 0, 0, tnx1); stageT(pB, ldsB1, 0, 1, tnx1);
        asm volatile("s_waitcnt vmcnt(6)" ::: "memory");
        __builtin_amdgcn_s_barrier();
        __builtin_amdgcn_s_setprio(1); mfma16<4, 0>(acc, a2F, bF);  __builtin_amdgcn_s_setprio(0);
        __builtin_amdgcn_s_barrier();
    }

#pragma unroll
    for (int mt = 0; mt < 8; ++mt)
#pragma unroll
        for (int nt = 0; nt < 4; ++nt)
#pragma unroll
            for (int r = 0; r < 4; ++r) {
                int rr = row0 + wm + mt * 16 + quad * 4 + r;
                int cc = col0 + wn + nt * 16 + lo;
                Pd[(size_t)rr * 4096 + cc] = f2b(acc[mt][nt][r]);
            }
}

// ---------------------------------------------------------------------------
// Fused: qkvb = Q0 + qkvb, then RoPE on the K region (verified r5).
// ---------------------------------------------------------------------------
__global__ __launch_bounds__(256) void qkv_addrope_k(
    const bf16* __restrict__ Q0, bf16* __restrict__ qkvb,
    const int* __restrict__ segpos)
{
    const int t = blockIdx.x;
    const int tid = threadIdx.x;
    const size_t row = (size_t)t * 4096;

    if (tid < 128 || tid >= 192) {
        // Q region (threads 0..127 -> 2048 elems) / V region (192..255 -> 1024)
        const size_t i = (tid < 128) ? row + (size_t)tid * 16
                                     : row + 3072 + (size_t)(tid - 192) * 16;
#pragma unroll
        for (int h = 0; h < 2; ++h) {
            short8 a = *(const short8*)(Q0 + i + h * 8);
            short8 b = *(const short8*)(qkvb + i + h * 8);
            const bf16* ap = (const bf16*)&a;
            const bf16* bp = (const bf16*)&b;
            bf16 o[8];
#pragma unroll
            for (int j = 0; j < 8; ++j) o[j] = f2b(b2f(ap[j]) + b2f(bp[j]));
            *(short8*)(qkvb + i + h * 8) = *(const short8*)o;
        }
    } else {
        // K region: 64 threads, each owns 8 first-half + 8 second-half elems
        const int k = tid - 128;
        const float pos = (float)segpos[t];
        const size_t base = row + 2048 + (size_t)(k >> 3) * 128 + (k & 7) * 8;
        short8 aF = *(const short8*)(Q0 + base);
        short8 bF = *(const short8*)(qkvb + base);
        short8 aS = *(const short8*)(Q0 + base + 64);
        short8 bS = *(const short8*)(qkvb + base + 64);
        const bf16* afp = (const bf16*)&aF;
        const bf16* bfp = (const bf16*)&bF;
        const bf16* asp = (const bf16*)&aS;
        const bf16* bsp = (const bf16*)&bS;
        bf16 oF[8], oS[8];
#pragma unroll
        for (int j = 0; j < 8; ++j) {
            const int hp = (k & 7) * 8 + j;
            float first  = b2f(afp[j]) + b2f(bfp[j]);
            float second = b2f(asp[j]) + b2f(bsp[j]);
            float ang = pos * __expf(-(float)hp * (1.0f / 64.0f) * LN_BASE);
            float sv, cv; __sincosf(ang, &sv, &cv);
            oF[j] = f2b(first * cv - second * sv);
            oS[j] = f2b(second * cv + first * sv);
        }
        *(short8*)(qkvb + base)      = *(const short8*)oF;
        *(short8*)(qkvb + base + 64) = *(const short8*)oS;
    }
}

// ---------------------------------------------------------------------------
// Split-K MFMA GEMM: grid.z selects K-half; writes fp32 partials.
// 128x128 tile (m97 structure); Ndim=2048, K-half = 1024.
// ---------------------------------------------------------------------------
__global__ __launch_bounds__(256) void mfma_gemm_splitk_k(
    const bf16* __restrict__ A, const bf16* __restrict__ BT,
    float* __restrict__ P0, float* __restrict__ P1)
{
    __shared__ alignas(16) bf16 As[128 * 32];
    __shared__ alignas(16) bf16 Bs[128 * 32];

    const int tid  = threadIdx.x;
    const int lane = tid & 63;
    const int wave = tid >> 6;
    const int lo   = lane & 15;
    const int quad = lane >> 4;
    const int row0 = blockIdx.x * 128;
    const int col0 = blockIdx.y * 128;
    const int kbeg = blockIdx.z * 1024;
    float* __restrict__ P = blockIdx.z ? P1 : P0;
    const int wm = (wave >> 1) * 64;
    const int wn = (wave & 1) * 64;

    const int lrow = lane >> 2;
    const int lcol = ((lane & 3) ^ ((lane >> 3) & 3)) * 8;
    const int swk  = (quad ^ ((lo >> 1) & 3)) * 8;

    floatx4 acc[4][4];
#pragma unroll
    for (int i = 0; i < 4; ++i)
#pragma unroll
        for (int j = 0; j < 4; ++j) acc[i][j] = (floatx4){0.f, 0.f, 0.f, 0.f};

    for (int k0 = kbeg; k0 < kbeg + 1024; k0 += 32) {
        __syncthreads();
#pragma unroll
        for (int i = 0; i < 2; ++i) {
            const int trow = wave * 32 + i * 16 + lrow;
            const bf16* ga = A  + (size_t)(row0 + trow) * 2048 + k0 + lcol;
            const bf16* gb = BT + (size_t)(col0 + trow) * 2048 + k0 + lcol;
            __builtin_amdgcn_global_load_lds(
                (const __attribute__((address_space(1))) void*)ga,
                (__attribute__((address_space(3))) void*)(As + (wave * 2 + i) * 512),
                16, 0, 0);
            __builtin_amdgcn_global_load_lds(
                (const __attribute__((address_space(1))) void*)gb,
                (__attribute__((address_space(3))) void*)(Bs + (wave * 2 + i) * 512),
                16, 0, 0);
        }
        __syncthreads();

        short8 af[4], bfr[4];
#pragma unroll
        for (int mt = 0; mt < 4; ++mt)
            af[mt] = *(const short8*)&As[(wm + mt * 16 + lo) * 32 + swk];
#pragma unroll
        for (int nt = 0; nt < 4; ++nt)
            bfr[nt] = *(const short8*)&Bs[(wn + nt * 16 + lo) * 32 + swk];
#pragma unroll
        for (int mt = 0; mt < 4; ++mt)
#pragma unroll
            for (int nt = 0; nt < 4; ++nt)
                acc[mt][nt] = __builtin_amdgcn_mfma_f32_16x16x32_bf16(
                    af[mt], bfr[nt], acc[mt][nt], 0, 0, 0);
    }

#pragma unroll
    for (int mt = 0; mt < 4; ++mt)
#pragma unroll
        for (int nt = 0; nt < 4; ++nt)
#pragma unroll
            for (int r = 0; r < 4; ++r) {
                int rr = row0 + wm + mt * 16 + quad * 4 + r;
                int cc = col0 + wn + nt * 16 + lo;
                P[(size_t)rr * 2048 + cc] = acc[mt][nt][r];
            }
}

// ---------------------------------------------------------------------------
// out = P0 + P1 (float4, 4 elems/thread)
// ---------------------------------------------------------------------------
__global__ __launch_bounds__(256) void add_out_k(
    const float* __restrict__ P0, const float* __restrict__ P1,
    float* __restrict__ out)
{
    const size_t i = ((size_t)blockIdx.x * 256 + threadIdx.x) * 4;
    float4 a = *(const float4*)(P0 + i);
    float4 b = *(const float4*)(P1 + i);
    float4 o = {a.x + b.x, a.y + b.y, a.z + b.z, a.w + b.w};
    *(float4*)(out + i) = o;
}

// ---------------------------------------------------------------------------
// Flash MFMA attention, fixed-m softmax, SPLIT-K over the key window (r8 fix:
// all scratch in-bounds; O-partials bf16 inside d_out, Lp fp32 in the dead
// WT_qkv region). Body = round-6 verified 8-wave GQA kernel; each block does
// HALF the key chunks (z in {0,1}; nch always even). Fixed-m softmax is
// linear: blocks write unnormalized bf16 O-partials + fp32 l-partials;
// attn_comb_k adds and normalizes. Grid 512 = 2 blocks/CU; ids [0,256) =
// heavy halves (17 chunks), [256,512) = light (avg 8.5) -> round-robin
// pairs heavy+light per CU (~25.5 chunks vs round-6's 34).
// ---------------------------------------------------------------------------
__global__ __launch_bounds__(512) void attn_k(
    const bf16* __restrict__ qkvb, const int* __restrict__ segpos,
    bf16* __restrict__ Op0, bf16* __restrict__ Op1, float* __restrict__ Lp)
{
    __shared__ alignas(16) bf16 Ks[2][32][136];
    __shared__ alignas(16) bf16 Vt[2][128][40];
    __shared__ alignas(16) bf16 Ps[8][16][40];

    const int id = blockIdx.x;
    int kh, bxi, z;
    if (id < 256) {            // heavy halves: bxi in [16,32)
        kh = id >> 5; const int t = id & 31; bxi = 16 + (t >> 1); z = t & 1;
    } else {                   // light halves: bxi in [0,16)
        const int u = id - 256;
        kh = u >> 5; const int t = u & 31; bxi = t >> 1; z = t & 1;
    }
    const int t0  = bxi * 64;
    const int tid  = threadIdx.x;
    const int lane = tid & 63;
    const int wave = tid >> 6;              // 0..7
    const int lo   = lane & 15;
    const int quad = lane >> 4;
    const int n    = kh * 2 + (wave >> 2);  // this wave's head
    const int twlo = t0 + (wave & 3) * 16;  // this wave's 16 query rows

    short8 qf[4];
    {
        const int tq = twlo + lo;
        const float pos = (float)segpos[tq];
        const bf16* qp = qkvb + (size_t)tq * 4096 + n * 128;
        float qv[4][8];
#pragma unroll
        for (int kc = 0; kc < 4; ++kc) {
            short8 raw = *(const short8*)(qp + kc * 32 + quad * 8);
            const bf16* rb = (const bf16*)&raw;
#pragma unroll
            for (int j = 0; j < 8; ++j) qv[kc][j] = b2f(rb[j]);
        }
#pragma unroll
        for (int kc = 0; kc < 2; ++kc)
#pragma unroll
            for (int j = 0; j < 8; ++j) {
                int hp = kc * 32 + quad * 8 + j;
                float ang = pos * __expf(-(float)hp * (1.0f / 64.0f) * LN_BASE);
                float sv, cv; __sincosf(ang, &sv, &cv);
                float first = qv[kc][j], second = qv[kc + 2][j];
                qv[kc][j]     = (first * cv - second * sv) * Q_SCALE;
                qv[kc + 2][j] = (second * cv + first * sv) * Q_SCALE;
            }
#pragma unroll
        for (int kc = 0; kc < 4; ++kc) {
            bf16 o[8];
#pragma unroll
            for (int j = 0; j < 8; ++j) o[j] = f2b(qv[kc][j]);
            qf[kc] = *(const short8*)o;
        }
    }

    floatx4 O[8];
#pragma unroll
    for (int i = 0; i < 8; ++i) O[i] = (floatx4){0.f, 0.f, 0.f, 0.f};
    float l_acc[4] = {0.f, 0.f, 0.f, 0.f};

    // staging roles (wave-uniform): tid<256 -> K, tid>=256 -> V
    const bool isK  = (tid < 256);
    const int  st   = tid & 255;
    const int key_a = st >> 3,       hd_a = (st & 7) * 16;
    const int kp2   = (st & 15) * 2, hd_b = (st >> 4) * 8;

    const int s_start = (t0 > 1023) ? (t0 - 1024) : 0;
    const int nch  = (t0 + 63 - s_start) / 32 + 1;   // always even
    const int half = nch >> 1;
    const int c_lo = z * half;
    const int c_hi = c_lo + half;

    const bf16* kg = qkvb + 2048 + kh * 128;
    const bf16* vg = qkvb + 3072 + kh * 128;

    short8 r0, r1;
    {
        const int fb = s_start + c_lo * 32;
        if (isK) {
            r0 = *(const short8*)(kg + (size_t)(fb + key_a) * 4096 + hd_a);
            r1 = *(const short8*)(kg + (size_t)(fb + key_a) * 4096 + hd_a + 8);
        } else {
            r0 = *(const short8*)(vg + (size_t)(fb + kp2) * 4096 + hd_b);
            r1 = *(const short8*)(vg + (size_t)(fb + kp2 + 1) * 4096 + hd_b);
        }
    }

    for (int c = c_lo; c < c_hi; ++c) {
        const int base = s_start + c * 32;
        const int buf = c & 1;

        if (isK) {
            *(short8*)&Ks[buf][key_a][hd_a]     = r0;
            *(short8*)&Ks[buf][key_a][hd_a + 8] = r1;
        } else {
#pragma unroll
            for (int i = 0; i < 8; ++i) {
                unsigned pk = (unsigned)(unsigned short)r0[i] |
                              ((unsigned)(unsigned short)r1[i] << 16);
                *(unsigned*)&Vt[buf][hd_b + i][kp2] = pk;
            }
        }
        if (c + 1 < c_hi) {
            const int nb = base + 32;
            if (isK) {
                r0 = *(const short8*)(kg + (size_t)(nb + key_a) * 4096 + hd_a);
                r1 = *(const short8*)(kg + (size_t)(nb + key_a) * 4096 + hd_a + 8);
            } else {
                r0 = *(const short8*)(vg + (size_t)(nb + kp2) * 4096 + hd_b);
                r1 = *(const short8*)(vg + (size_t)(nb + kp2 + 1) * 4096 + hd_b);
            }
        }
        __syncthreads();

        const int dbase = twlo - base;
        if (dbase >= -15 && dbase <= 1054) {
            floatx4 S0 = (floatx4){0.f, 0.f, 0.f, 0.f};
            floatx4 S1 = (floatx4){0.f, 0.f, 0.f, 0.f};
#pragma unroll
            for (int kc = 0; kc < 4; ++kc) {
                short8 b0 = *(const short8*)&Ks[buf][lo][kc * 32 + quad * 8];
                short8 b1 = *(const short8*)&Ks[buf][16 + lo][kc * 32 + quad * 8];
                S0 = __builtin_amdgcn_mfma_f32_16x16x32_bf16(qf[kc], b0, S0, 0, 0, 0);
                S1 = __builtin_amdgcn_mfma_f32_16x16x32_bf16(qf[kc], b1, S1, 0, 0, 0);
            }
            short8 vfrag[8];
#pragma unroll
            for (int nt = 0; nt < 8; ++nt)
                vfrag[nt] = *(const short8*)&Vt[buf][nt * 16 + lo][quad * 8];

            const bool need_mask = !(dbase >= 31 && dbase <= 1008);
            const int dq = dbase + quad * 4 - lo;
            float lg[2][4];
#pragma unroll
            for (int tau = 0; tau < 2; ++tau) {
#pragma unroll
                for (int r = 0; r < 4; ++r) {
                    float sv = (tau == 0) ? S0[r] : S1[r];
                    float ax = fabsf(sv) * (2.0f / SOFT_CAP);
                    float e2 = __expf(-ax);
                    float th = (1.0f - e2) * __builtin_amdgcn_rcpf(1.0f + e2);
                    float l  = copysignf(SOFT_CAP * th, sv);
                    float p  = __expf(l);
                    if (need_mask) {
                        int d = dq + r - tau * 16;
                        if ((unsigned)d > 1023u) p = 0.f;
                    }
                    lg[tau][r] = p;
                }
            }
#pragma unroll
            for (int r = 0; r < 4; ++r) l_acc[r] += lg[0][r] + lg[1][r];

#pragma unroll
            for (int tau = 0; tau < 2; ++tau)
#pragma unroll
                for (int r = 0; r < 4; ++r)
                    Ps[wave][quad * 4 + r][tau * 16 + lo] = f2b(lg[tau][r]);

            short8 pfrag = *(const short8*)&Ps[wave][lo][quad * 8];
#pragma unroll
            for (int nt = 0; nt < 8; ++nt)
                O[nt] = __builtin_amdgcn_mfma_f32_16x16x32_bf16(pfrag, vfrag[nt], O[nt], 0, 0, 0);
        }
    }

    // partial epilogue: unnormalized bf16 O + fp32 per-row l
    bf16* __restrict__ Op = z ? Op1 : Op0;
#pragma unroll
    for (int nt = 0; nt < 8; ++nt)
#pragma unroll
        for (int r = 0; r < 4; ++r) {
            int t = twlo + quad * 4 + r;
            Op[(size_t)t * 2048 + n * 128 + nt * 16 + lo] = f2b(O[nt][r]);
        }

#pragma unroll
    for (int xm = 1; xm < 16; xm <<= 1)
#pragma unroll
        for (int r = 0; r < 4; ++r) l_acc[r] += __shfl_xor(l_acc[r], xm, 64);
    if (lo == 0) {
#pragma unroll
        for (int r = 0; r < 4; ++r) {
            int t = twlo + quad * 4 + r;
            Lp[((size_t)z * 2048 + t) * 16 + n] = l_acc[r];
        }
    }
}

// ---------------------------------------------------------------------------
// ebuf[t][n*128+c] = (Op0 + Op1) / (l0 + l1)  (bf16 partials in, bf16 out)
// ---------------------------------------------------------------------------
__global__ __launch_bounds__(256) void attn_comb_k(
    const bf16* __restrict__ Op0, const bf16* __restrict__ Op1,
    const float* __restrict__ Lp, bf16* __restrict__ ebuf)
{
    const int t   = blockIdx.x;
    const int tid = threadIdx.x;
    const int n   = tid >> 4;
    const float l = Lp[(size_t)t * 16 + n] + Lp[(size_t)(2048 + t) * 16 + n];
    const float invl = 1.0f / l;
    const size_t base = (size_t)t * 2048 + (size_t)tid * 8;
    short8 a = *(const short8*)(Op0 + base);
    short8 b = *(const short8*)(Op1 + base);
    const bf16* ap = (const bf16*)&a;
    const bf16* bp = (const bf16*)&b;
    bf16 o[8];
#pragma unroll
    for (int j = 0; j < 8; ++j)
        o[j] = f2b((b2f(ap[j]) + b2f(bp[j])) * invl);
    *(short8*)(ebuf + base) = *(const short8*)o;
}

// ---------------------------------------------------------------------------
extern "C" void kernel_launch(void* const* d_in, const int* in_sizes, int n_in,
                              void* d_out, int out_size, void* d_ws, size_t ws_size,
                              hipStream_t stream)
{
    const float* x   = (const float*)d_in[0];
    const int*  segp = (const int*)d_in[1];
    // d_in[2] = attn_mask (bool) -- redundant with causal+window predicate, ignored
    const float* qk  = (const float*)d_in[3];
    const float* kvk = (const float*)d_in[4];
    const float* ok  = (const float*)d_in[5];

    // Workspace (48 MB): A=xb/ebuf[0,8) | B=WT_qkv[8,24) | C=WT_out[24,32) | D=qkvb[32,48)
    // d_out (16 MB exactly):
    //   - Q0 (bf16 qkv z=0 partial) until qkv_addrope_k
    //   - then Op0=[0,8MB) Op1=[8,16MB) bf16 attn O-partials (ALL in-bounds; r8 OOB fix)
    //   - finally the fp32 output (add_out_k, last)
    // Lp (fp32 256KB) lives at B base (WT_qkv dead after gemm_qkv).
    // After attn_comb: B -> P0, D -> P1 (out-proj split-K fp32 partials).
    bf16* xb     = (bf16*)d_ws;
    bf16* ebuf   = xb;
    bf16* WT_qkv = xb + (size_t)4 * 1024 * 1024;
    bf16* WT_out = WT_qkv + (size_t)8 * 1024 * 1024;
    bf16* qkvb   = WT_out + (size_t)4 * 1024 * 1024;
    bf16* Q0     = (bf16*)d_out;                         // qkv split-K partial (z=0)
    bf16* Op0    = (bf16*)d_out;                         // attn O-partial z=0
    bf16* Op1    = (bf16*)d_out + (size_t)4 * 1024 * 1024;  // attn O-partial z=1
    float* Lp    = (float*)WT_qkv;                       // attn l-partials (256KB)
    float* P0    = (float*)WT_qkv;
    float* P1    = (float*)qkvb;
    float* outp  = (float*)d_out;

    prep_k<<<dim3(14336), dim3(256), 0, stream>>>(x, qk, kvk, ok, xb, WT_qkv, WT_out);
    gemm_qkv_8ph_k<<<dim3(128, 2), dim3(512), 0, stream>>>(xb, WT_qkv, Q0, qkvb);
    qkv_addrope_k<<<dim3(T_DIM), dim3(256), 0, stream>>>(Q0, qkvb, segp);
    attn_k<<<dim3(512), dim3(512), 0, stream>>>(qkvb, segp, Op0, Op1, Lp);
    attn_comb_k<<<dim3(T_DIM), dim3(256), 0, stream>>>(Op0, Op1, Lp, ebuf);
    mfma_gemm_splitk_k<<<dim3(16, 16, 2), dim3(256), 0, stream>>>(
        ebuf, WT_out, P0, P1);
    add_out_k<<<dim3(4096), dim3(256), 0, stream>>>(P0, P1, outp);
}

// Round 10
// 239.805 us; speedup vs baseline: 1.1543x; 1.0418x over previous
//
#include <hip/hip_runtime.h>
#include <hip/hip_bf16.h>
#include <math.h>

// Problem constants (B=1)
#define T_DIM 2048
#define D_DIM 2048
#define N_HEADS 16
#define K_HEADS 8
#define H_DIM 128
#define WINDOW_SZ 1024
#define SOFT_CAP 50.0f
#define Q_SCALE 0.08838834764831845f   // 1/sqrt(128)
#define LN_BASE 9.210340371976184f     // ln(10000)

typedef __hip_bfloat16 bf16;
typedef __attribute__((ext_vector_type(8))) short short8;
typedef __attribute__((ext_vector_type(4))) float floatx4;

static __device__ __forceinline__ bf16 f2b(float v) { return __float2bfloat16(v); }
static __device__ __forceinline__ float b2f(bf16 v) { return __bfloat162float(v); }

// ---------------------------------------------------------------------------
// Fused prep: 1D grid.
//   [0, 8192)     : qkv weight transpose (32 matrices, 2048x128 -> rows z*128 of WT_qkv)
//   [8192, 12288) : out weight transpose (16 matrices, 128x2048 -> cols z*128 of WT_out)
//   [12288,14336) : x fp32 -> bf16 copy
// ---------------------------------------------------------------------------
__global__ __launch_bounds__(256) void prep_k(
    const float* __restrict__ x, const float* __restrict__ qk,
    const float* __restrict__ kvk, const float* __restrict__ ok,
    bf16* __restrict__ xb, bf16* __restrict__ WT_qkv, bf16* __restrict__ WT_out)
{
    __shared__ float tile[32][33];
    const int b = blockIdx.x;
    const int tid = threadIdx.x;
    const int tx = tid & 31, ty = tid >> 5;

    if (b < 8192) {
        const int z = b >> 8, rem = b & 255;
        const int c0 = (rem & 3) * 32;        // over H (128)
        const int r0 = (rem >> 2) * 32;       // over D (2048)
        const float* src = (z < 16) ? qk + (size_t)z * D_DIM * H_DIM
                                    : kvk + (size_t)(z - 16) * D_DIM * H_DIM;
        bf16* dst = WT_qkv + (size_t)z * 128 * 2048;
#pragma unroll
        for (int i = 0; i < 4; ++i)
            tile[ty + i * 8][tx] = src[(size_t)(r0 + ty + i * 8) * H_DIM + c0 + tx];
        __syncthreads();
#pragma unroll
        for (int i = 0; i < 4; ++i)
            dst[(size_t)(c0 + ty + i * 8) * 2048 + r0 + tx] = f2b(tile[tx][ty + i * 8]);
    } else if (b < 12288) {
        const int b2 = b - 8192;
        const int z = b2 >> 8, rem = b2 & 255;
        const int c0 = (rem & 63) * 32;       // over D (2048)
        const int r0 = (rem >> 6) * 32;       // over H (128)
        const float* src = ok + (size_t)z * H_DIM * D_DIM;
        bf16* dst = WT_out + (size_t)z * H_DIM;
#pragma unroll
        for (int i = 0; i < 4; ++i)
            tile[ty + i * 8][tx] = src[(size_t)(r0 + ty + i * 8) * D_DIM + c0 + tx];
        __syncthreads();
#pragma unroll
        for (int i = 0; i < 4; ++i)
            dst[(size_t)(c0 + ty + i * 8) * 2048 + r0 + tx] = f2b(tile[tx][ty + i * 8]);
    } else {
        const size_t i = ((size_t)(b - 12288) * 256 + tid) * 8;
        float4 a = *(const float4*)(x + i);
        float4 bb = *(const float4*)(x + i + 4);
        bf16 o[8] = {f2b(a.x), f2b(a.y), f2b(a.z), f2b(a.w),
                     f2b(bb.x), f2b(bb.y), f2b(bb.z), f2b(bb.w)};
        *(short8*)(xb + i) = *(const short8*)o;
    }
}

// ---------------------------------------------------------------------------
// QKV GEMM, round-9 restructure: BM=128 x BN=256, FULL K=2048 (no split-K,
// no partials, no add pass). 256 WGs = 16 row x 16 col panels, 1/CU.
// Triple-buffered LDS (3 x 48KB = 144KB <= 160KB), 2 phases per K-tile
// (BK=64), 2-tile stage lookahead, counted vmcnt(6) (= next tile's 6 loads
// in flight). Staging always targets buf(t+2)=buf(t-1), whose reads
// completed >=2 barriers earlier (race-free by construction).
// XCD map: wg&7 pins 2 B col-panels (2MB, L2-resident, read 16x) per XCD.
// Swizzle pair + read helpers identical to the r2-verified 8-phase kernel.
// ---------------------------------------------------------------------------
static __device__ __forceinline__ void stage64(const bf16* __restrict__ gsrc,
                                               bf16* ldst, int r, int kt)
{
    __builtin_amdgcn_global_load_lds(
        (const __attribute__((address_space(1))) void*)
            (gsrc + (size_t)(r * 64) * 2048 + (size_t)kt * 64),
        (__attribute__((address_space(3))) void*)(ldst + r * 4096),
        16, 0, 0);
}

template <int MTB>
static __device__ __forceinline__ void readA4(short8 (&dst)[4][2], const bf16* base,
                                              int rlo, const int (&cs)[2])
{
#pragma unroll
    for (int mt = 0; mt < 4; ++mt)
#pragma unroll
        for (int ks = 0; ks < 2; ++ks)
            dst[mt][ks] = *(const short8*)&base[(rlo + (MTB + mt) * 16) * 64 + cs[ks]];
}

template <int NTB>
static __device__ __forceinline__ void readB2(short8 (&dst)[2][2], const bf16* base,
                                              int rlo, const int (&cs)[2])
{
#pragma unroll
    for (int n2 = 0; n2 < 2; ++n2)
#pragma unroll
        for (int ks = 0; ks < 2; ++ks)
            dst[n2][ks] = *(const short8*)&base[(rlo + (NTB + n2) * 16) * 64 + cs[ks]];
}

template <int NB>
static __device__ __forceinline__ void mfma16b(floatx4 (&acc)[4][4],
                                               const short8 (&af)[4][2],
                                               const short8 (&bf)[2][2])
{
#pragma unroll
    for (int mt = 0; mt < 4; ++mt)
#pragma unroll
        for (int n2 = 0; n2 < 2; ++n2) {
            acc[mt][NB + n2] = __builtin_amdgcn_mfma_f32_16x16x32_bf16(
                af[mt][0], bf[n2][0], acc[mt][NB + n2], 0, 0, 0);
            acc[mt][NB + n2] = __builtin_amdgcn_mfma_f32_16x16x32_bf16(
                af[mt][1], bf[n2][1], acc[mt][NB + n2], 0, 0, 0);
        }
}

__global__ __launch_bounds__(512, 2) void gemm_qkv_3buf_k(
    const bf16* __restrict__ A, const bf16* __restrict__ BT, bf16* __restrict__ C)
{
    __shared__ alignas(16) bf16 lds[3][24576];   // per buf: A[0,8192) B[8192,24576)

    const int tid  = threadIdx.x;
    const int lane = tid & 63;
    const int wave = tid >> 6;
    const int lo   = lane & 15;
    const int quad = lane >> 4;

    const int wg   = blockIdx.x;
    const int nn   = (wg & 7) * 2 + ((wg >> 3) & 1);   // col panel, XCD-pinned
    const int m    = wg >> 4;                           // row panel
    const int row0 = m * 128;
    const int col0 = nn * 256;

    const int wm   = (wave >> 2) * 64;    // 2 M-groups of 64
    const int wn   = (wave & 3) * 64;     // 4 N-groups of 64
    const int wmlo = wm + lo, wnlo = wn + lo;

    // staging: per-thread pre-swizzled global source (lane-constant XOR)
    const int r_y   = wave * 8 + (lane >> 3);                   // 0..63
    const int c_src = ((lane & 7) ^ ((lane >> 3) & 7)) * 8;     // elements
    const bf16* pA = A  + (size_t)(row0 + r_y) * 2048 + c_src;
    const bf16* pB = BT + (size_t)(col0 + r_y) * 2048 + c_src;

    // rotating buffer base pointers (read-side; stage adds wave*512)
    bf16 *cA = &lds[0][0], *cB = &lds[0][8192];
    bf16 *nA = &lds[1][0], *nB = &lds[1][8192];
    bf16 *sA = &lds[2][0], *sB = &lds[2][8192];
    const int wo = wave * 512;

    const int cs[2] = { (quad * 8) ^ ((lo & 7) << 3),
                        (32 + quad * 8) ^ ((lo & 7) << 3) };

    floatx4 acc[4][4];
#pragma unroll
    for (int i = 0; i < 4; ++i)
#pragma unroll
        for (int j = 0; j < 4; ++j) acc[i][j] = (floatx4){0.f, 0.f, 0.f, 0.f};

    // prologue: tiles 0 and 1 (6 loads each); vmcnt(6) -> tile 0 landed
    stage64(pA, cA + wo, 0, 0); stage64(pA, cA + wo, 1, 0);
    stage64(pB, cB + wo, 0, 0); stage64(pB, cB + wo, 1, 0);
    stage64(pB, cB + wo, 2, 0); stage64(pB, cB + wo, 3, 0);
    stage64(pA, nA + wo, 0, 1); stage64(pA, nA + wo, 1, 1);
    stage64(pB, nB + wo, 0, 1); stage64(pB, nB + wo, 1, 1);
    stage64(pB, nB + wo, 2, 1); stage64(pB, nB + wo, 3, 1);
    asm volatile("s_waitcnt vmcnt(6)" ::: "memory");
    __builtin_amdgcn_s_barrier();

    short8 aF[4][2], bF[2][2], b2F[2][2];

#pragma unroll 1
    for (int t = 0; t < 32; ++t) {
        // phase A: read A + B-low of buf(t); stage A(t+2) into buf(t-1)
        readA4<0>(aF, cA, wmlo, cs);
        readB2<0>(bF, cB, wnlo, cs);
        if (t < 30) {
            stage64(pA, sA + wo, 0, t + 2);
            stage64(pA, sA + wo, 1, t + 2);
        }
        __builtin_amdgcn_s_barrier();
        __builtin_amdgcn_s_setprio(1); mfma16b<0>(acc, aF, bF);  __builtin_amdgcn_s_setprio(0);
        __builtin_amdgcn_s_barrier();

        // phase B: read B-high of buf(t); stage B(t+2); counted vmcnt
        readB2<2>(b2F, cB, wnlo, cs);
        if (t < 30) {
            stage64(pB, sB + wo, 0, t + 2); stage64(pB, sB + wo, 1, t + 2);
            stage64(pB, sB + wo, 2, t + 2); stage64(pB, sB + wo, 3, t + 2);
            asm volatile("s_waitcnt vmcnt(6)" ::: "memory");   // tile t+1 landed
        } else {
            asm volatile("s_waitcnt vmcnt(0)" ::: "memory");
        }
        __builtin_amdgcn_s_barrier();
        __builtin_amdgcn_s_setprio(1); mfma16b<2>(acc, aF, b2F); __builtin_amdgcn_s_setprio(0);
        __builtin_amdgcn_s_barrier();

        // rotate buffers: cur <- next <- spare <- cur
        bf16* tA = cA; cA = nA; nA = sA; sA = tA;
        bf16* tB = cB; cB = nB; nB = sB; sB = tB;
    }

    // epilogue: C write (bf16, Ndim=4096)
#pragma unroll
    for (int mt = 0; mt < 4; ++mt)
#pragma unroll
        for (int nt = 0; nt < 4; ++nt)
#pragma unroll
            for (int r = 0; r < 4; ++r) {
                int rr = row0 + wm + mt * 16 + quad * 4 + r;
                int cc = col0 + wn + nt * 16 + lo;
                C[(size_t)rr * 4096 + cc] = f2b(acc[mt][nt][r]);
            }
}

// ---------------------------------------------------------------------------
// RoPE on K only (q-rope fused into attn). 512 pairs per t. (verified r0)
// ---------------------------------------------------------------------------
__global__ __launch_bounds__(256) void rope_kk(bf16* __restrict__ qkvb,
                                               const int* __restrict__ segpos)
{
    const int t = blockIdx.x;
    const float pos = (float)segpos[t];
    bf16* rowp = qkvb + (size_t)t * 4096 + 2048;
#pragma unroll
    for (int it = 0; it < 2; ++it) {
        int p = threadIdx.x + it * 256;
        int hp = p & 63;
        bf16* buf = rowp + (p >> 6) * 128;
        float fraction = (float)hp * (1.0f / 64.0f);
        float inv_ts = __expf(-fraction * LN_BASE);
        float ang = pos * inv_ts;
        float sv, cv; __sincosf(ang, &sv, &cv);
        float first  = b2f(buf[hp]);
        float second = b2f(buf[hp + 64]);
        buf[hp]      = f2b(first * cv - second * sv);
        buf[hp + 64] = f2b(second * cv + first * sv);
    }
}

// ---------------------------------------------------------------------------
// Split-K MFMA GEMM: grid.z selects K-half; writes fp32 partials.
// 128x128 tile (m97 structure); Ndim=2048, K-half = 1024.
// ---------------------------------------------------------------------------
__global__ __launch_bounds__(256) void mfma_gemm_splitk_k(
    const bf16* __restrict__ A, const bf16* __restrict__ BT,
    float* __restrict__ P0, float* __restrict__ P1)
{
    __shared__ alignas(16) bf16 As[128 * 32];
    __shared__ alignas(16) bf16 Bs[128 * 32];

    const int tid  = threadIdx.x;
    const int lane = tid & 63;
    const int wave = tid >> 6;
    const int lo   = lane & 15;
    const int quad = lane >> 4;
    const int row0 = blockIdx.x * 128;
    const int col0 = blockIdx.y * 128;
    const int kbeg = blockIdx.z * 1024;
    float* __restrict__ P = blockIdx.z ? P1 : P0;
    const int wm = (wave >> 1) * 64;
    const int wn = (wave & 1) * 64;

    const int lrow = lane >> 2;
    const int lcol = ((lane & 3) ^ ((lane >> 3) & 3)) * 8;
    const int swk  = (quad ^ ((lo >> 1) & 3)) * 8;

    floatx4 acc[4][4];
#pragma unroll
    for (int i = 0; i < 4; ++i)
#pragma unroll
        for (int j = 0; j < 4; ++j) acc[i][j] = (floatx4){0.f, 0.f, 0.f, 0.f};

    for (int k0 = kbeg; k0 < kbeg + 1024; k0 += 32) {
        __syncthreads();
#pragma unroll
        for (int i = 0; i < 2; ++i) {
            const int trow = wave * 32 + i * 16 + lrow;
            const bf16* ga = A  + (size_t)(row0 + trow) * 2048 + k0 + lcol;
            const bf16* gb = BT + (size_t)(col0 + trow) * 2048 + k0 + lcol;
            __builtin_amdgcn_global_load_lds(
                (const __attribute__((address_space(1))) void*)ga,
                (__attribute__((address_space(3))) void*)(As + (wave * 2 + i) * 512),
                16, 0, 0);
            __builtin_amdgcn_global_load_lds(
                (const __attribute__((address_space(1))) void*)gb,
                (__attribute__((address_space(3))) void*)(Bs + (wave * 2 + i) * 512),
                16, 0, 0);
        }
        __syncthreads();

        short8 af[4], bfr[4];
#pragma unroll
        for (int mt = 0; mt < 4; ++mt)
            af[mt] = *(const short8*)&As[(wm + mt * 16 + lo) * 32 + swk];
#pragma unroll
        for (int nt = 0; nt < 4; ++nt)
            bfr[nt] = *(const short8*)&Bs[(wn + nt * 16 + lo) * 32 + swk];
#pragma unroll
        for (int mt = 0; mt < 4; ++mt)
#pragma unroll
            for (int nt = 0; nt < 4; ++nt)
                acc[mt][nt] = __builtin_amdgcn_mfma_f32_16x16x32_bf16(
                    af[mt], bfr[nt], acc[mt][nt], 0, 0, 0);
    }

#pragma unroll
    for (int mt = 0; mt < 4; ++mt)
#pragma unroll
        for (int nt = 0; nt < 4; ++nt)
#pragma unroll
            for (int r = 0; r < 4; ++r) {
                int rr = row0 + wm + mt * 16 + quad * 4 + r;
                int cc = col0 + wn + nt * 16 + lo;
                P[(size_t)rr * 2048 + cc] = acc[mt][nt][r];
            }
}

// ---------------------------------------------------------------------------
// out = P0 + P1 (float4, 4 elems/thread)
// ---------------------------------------------------------------------------
__global__ __launch_bounds__(256) void add_out_k(
    const float* __restrict__ P0, const float* __restrict__ P1,
    float* __restrict__ out)
{
    const size_t i = ((size_t)blockIdx.x * 256 + threadIdx.x) * 4;
    float4 a = *(const float4*)(P0 + i);
    float4 b = *(const float4*)(P1 + i);
    float4 o = {a.x + b.x, a.y + b.y, a.z + b.z, a.w + b.w};
    *(float4*)(out + i) = o;
}

// ---------------------------------------------------------------------------
// Flash MFMA attention, fixed-m softmax, SPLIT-K over the key window
// (verified r9). Body = round-6 verified 8-wave GQA kernel; each block does
// HALF the key chunks (z in {0,1}; nch always even). Fixed-m softmax is
// linear: blocks write unnormalized bf16 O-partials + fp32 l-partials;
// attn_comb_k adds and normalizes. Grid 512 = 2 blocks/CU; ids [0,256) =
// heavy halves (17 chunks), [256,512) = light (avg 8.5) -> round-robin
// pairs heavy+light per CU.
// ---------------------------------------------------------------------------
__global__ __launch_bounds__(512) void attn_k(
    const bf16* __restrict__ qkvb, const int* __restrict__ segpos,
    bf16* __restrict__ Op0, bf16* __restrict__ Op1, float* __restrict__ Lp)
{
    __shared__ alignas(16) bf16 Ks[2][32][136];
    __shared__ alignas(16) bf16 Vt[2][128][40];
    __shared__ alignas(16) bf16 Ps[8][16][40];

    const int id = blockIdx.x;
    int kh, bxi, z;
    if (id < 256) {            // heavy halves: bxi in [16,32)
        kh = id >> 5; const int t = id & 31; bxi = 16 + (t >> 1); z = t & 1;
    } else {                   // light halves: bxi in [0,16)
        const int u = id - 256;
        kh = u >> 5; const int t = u & 31; bxi = t >> 1; z = t & 1;
    }
    const int t0  = bxi * 64;
    const int tid  = threadIdx.x;
    const int lane = tid & 63;
    const int wave = tid >> 6;              // 0..7
    const int lo   = lane & 15;
    const int quad = lane >> 4;
    const int n    = kh * 2 + (wave >> 2);  // this wave's head
    const int twlo = t0 + (wave & 3) * 16;  // this wave's 16 query rows

    short8 qf[4];
    {
        const int tq = twlo + lo;
        const float pos = (float)segpos[tq];
        const bf16* qp = qkvb + (size_t)tq * 4096 + n * 128;
        float qv[4][8];
#pragma unroll
        for (int kc = 0; kc < 4; ++kc) {
            short8 raw = *(const short8*)(qp + kc * 32 + quad * 8);
            const bf16* rb = (const bf16*)&raw;
#pragma unroll
            for (int j = 0; j < 8; ++j) qv[kc][j] = b2f(rb[j]);
        }
#pragma unroll
        for (int kc = 0; kc < 2; ++kc)
#pragma unroll
            for (int j = 0; j < 8; ++j) {
                int hp = kc * 32 + quad * 8 + j;
                float ang = pos * __expf(-(float)hp * (1.0f / 64.0f) * LN_BASE);
                float sv, cv; __sincosf(ang, &sv, &cv);
                float first = qv[kc][j], second = qv[kc + 2][j];
                qv[kc][j]     = (first * cv - second * sv) * Q_SCALE;
                qv[kc + 2][j] = (second * cv + first * sv) * Q_SCALE;
            }
#pragma unroll
        for (int kc = 0; kc < 4; ++kc) {
            bf16 o[8];
#pragma unroll
            for (int j = 0; j < 8; ++j) o[j] = f2b(qv[kc][j]);
            qf[kc] = *(const short8*)o;
        }
    }

    floatx4 O[8];
#pragma unroll
    for (int i = 0; i < 8; ++i) O[i] = (floatx4){0.f, 0.f, 0.f, 0.f};
    float l_acc[4] = {0.f, 0.f, 0.f, 0.f};

    // staging roles (wave-uniform): tid<256 -> K, tid>=256 -> V
    const bool isK  = (tid < 256);
    const int  st   = tid & 255;
    const int key_a = st >> 3,       hd_a = (st & 7) * 16;
    const int kp2   = (st & 15) * 2, hd_b = (st >> 4) * 8;

    const int s_start = (t0 > 1023) ? (t0 - 1024) : 0;
    const int nch  = (t0 + 63 - s_start) / 32 + 1;   // always even
    const int half = nch >> 1;
    const int c_lo = z * half;
    const int c_hi = c_lo + half;

    const bf16* kg = qkvb + 2048 + kh * 128;
    const bf16* vg = qkvb + 3072 + kh * 128;

    short8 r0, r1;
    {
        const int fb = s_start + c_lo * 32;
        if (isK) {
            r0 = *(const short8*)(kg + (size_t)(fb + key_a) * 4096 + hd_a);
            r1 = *(const short8*)(kg + (size_t)(fb + key_a) * 4096 + hd_a + 8);
        } else {
            r0 = *(const short8*)(vg + (size_t)(fb + kp2) * 4096 + hd_b);
            r1 = *(const short8*)(vg + (size_t)(fb + kp2 + 1) * 4096 + hd_b);
        }
    }

    for (int c = c_lo; c < c_hi; ++c) {
        const int base = s_start + c * 32;
        const int buf = c & 1;

        if (isK) {
            *(short8*)&Ks[buf][key_a][hd_a]     = r0;
            *(short8*)&Ks[buf][key_a][hd_a + 8] = r1;
        } else {
#pragma unroll
            for (int i = 0; i < 8; ++i) {
                unsigned pk = (unsigned)(unsigned short)r0[i] |
                              ((unsigned)(unsigned short)r1[i] << 16);
                *(unsigned*)&Vt[buf][hd_b + i][kp2] = pk;
            }
        }
        if (c + 1 < c_hi) {
            const int nb = base + 32;
            if (isK) {
                r0 = *(const short8*)(kg + (size_t)(nb + key_a) * 4096 + hd_a);
                r1 = *(const short8*)(kg + (size_t)(nb + key_a) * 4096 + hd_a + 8);
            } else {
                r0 = *(const short8*)(vg + (size_t)(nb + kp2) * 4096 + hd_b);
                r1 = *(const short8*)(vg + (size_t)(nb + kp2 + 1) * 4096 + hd_b);
            }
        }
        __syncthreads();

        const int dbase = twlo - base;
        if (dbase >= -15 && dbase <= 1054) {
            floatx4 S0 = (floatx4){0.f, 0.f, 0.f, 0.f};
            floatx4 S1 = (floatx4){0.f, 0.f, 0.f, 0.f};
#pragma unroll
            for (int kc = 0; kc < 4; ++kc) {
                short8 b0 = *(const short8*)&Ks[buf][lo][kc * 32 + quad * 8];
                short8 b1 = *(const short8*)&Ks[buf][16 + lo][kc * 32 + quad * 8];
                S0 = __builtin_amdgcn_mfma_f32_16x16x32_bf16(qf[kc], b0, S0, 0, 0, 0);
                S1 = __builtin_amdgcn_mfma_f32_16x16x32_bf16(qf[kc], b1, S1, 0, 0, 0);
            }
            short8 vfrag[8];
#pragma unroll
            for (int nt = 0; nt < 8; ++nt)
                vfrag[nt] = *(const short8*)&Vt[buf][nt * 16 + lo][quad * 8];

            const bool need_mask = !(dbase >= 31 && dbase <= 1008);
            const int dq = dbase + quad * 4 - lo;
            float lg[2][4];
#pragma unroll
            for (int tau = 0; tau < 2; ++tau) {
#pragma unroll
                for (int r = 0; r < 4; ++r) {
                    float sv = (tau == 0) ? S0[r] : S1[r];
                    float ax = fabsf(sv) * (2.0f / SOFT_CAP);
                    float e2 = __expf(-ax);
                    float th = (1.0f - e2) * __builtin_amdgcn_rcpf(1.0f + e2);
                    float l  = copysignf(SOFT_CAP * th, sv);
                    float p  = __expf(l);
                    if (need_mask) {
                        int d = dq + r - tau * 16;
                        if ((unsigned)d > 1023u) p = 0.f;
                    }
                    lg[tau][r] = p;
                }
            }
#pragma unroll
            for (int r = 0; r < 4; ++r) l_acc[r] += lg[0][r] + lg[1][r];

#pragma unroll
            for (int tau = 0; tau < 2; ++tau)
#pragma unroll
                for (int r = 0; r < 4; ++r)
                    Ps[wave][quad * 4 + r][tau * 16 + lo] = f2b(lg[tau][r]);

            short8 pfrag = *(const short8*)&Ps[wave][lo][quad * 8];
#pragma unroll
            for (int nt = 0; nt < 8; ++nt)
                O[nt] = __builtin_amdgcn_mfma_f32_16x16x32_bf16(pfrag, vfrag[nt], O[nt], 0, 0, 0);
        }
    }

    // partial epilogue: unnormalized bf16 O + fp32 per-row l
    bf16* __restrict__ Op = z ? Op1 : Op0;
#pragma unroll
    for (int nt = 0; nt < 8; ++nt)
#pragma unroll
        for (int r = 0; r < 4; ++r) {
            int t = twlo + quad * 4 + r;
            Op[(size_t)t * 2048 + n * 128 + nt * 16 + lo] = f2b(O[nt][r]);
        }

#pragma unroll
    for (int xm = 1; xm < 16; xm <<= 1)
#pragma unroll
        for (int r = 0; r < 4; ++r) l_acc[r] += __shfl_xor(l_acc[r], xm, 64);
    if (lo == 0) {
#pragma unroll
        for (int r = 0; r < 4; ++r) {
            int t = twlo + quad * 4 + r;
            Lp[((size_t)z * 2048 + t) * 16 + n] = l_acc[r];
        }
    }
}

// ---------------------------------------------------------------------------
// ebuf[t][n*128+c] = (Op0 + Op1) / (l0 + l1)  (bf16 partials in, bf16 out)
// ---------------------------------------------------------------------------
__global__ __launch_bounds__(256) void attn_comb_k(
    const bf16* __restrict__ Op0, const bf16* __restrict__ Op1,
    const float* __restrict__ Lp, bf16* __restrict__ ebuf)
{
    const int t   = blockIdx.x;
    const int tid = threadIdx.x;
    const int n   = tid >> 4;
    const float l = Lp[(size_t)t * 16 + n] + Lp[(size_t)(2048 + t) * 16 + n];
    const float invl = 1.0f / l;
    const size_t base = (size_t)t * 2048 + (size_t)tid * 8;
    short8 a = *(const short8*)(Op0 + base);
    short8 b = *(const short8*)(Op1 + base);
    const bf16* ap = (const bf16*)&a;
    const bf16* bp = (const bf16*)&b;
    bf16 o[8];
#pragma unroll
    for (int j = 0; j < 8; ++j)
        o[j] = f2b((b2f(ap[j]) + b2f(bp[j])) * invl);
    *(short8*)(ebuf + base) = *(const short8*)o;
}

// ---------------------------------------------------------------------------
extern "C" void kernel_launch(void* const* d_in, const int* in_sizes, int n_in,
                              void* d_out, int out_size, void* d_ws, size_t ws_size,
                              hipStream_t stream)
{
    const float* x   = (const float*)d_in[0];
    const int*  segp = (const int*)d_in[1];
    // d_in[2] = attn_mask (bool) -- redundant with causal+window predicate, ignored
    const float* qk  = (const float*)d_in[3];
    const float* kvk = (const float*)d_in[4];
    const float* ok  = (const float*)d_in[5];

    // Workspace (48 MB): A=xb/ebuf[0,8) | B=WT_qkv[8,24) | C=WT_out[24,32) | D=qkvb[32,48)
    // d_out (16 MB exactly):
    //   - Op0=[0,8MB) Op1=[8,16MB) bf16 attn O-partials (in-bounds)
    //   - finally the fp32 output (add_out_k, last)
    // Lp (fp32 256KB) lives at B base (WT_qkv dead after gemm_qkv).
    // After attn_comb: B -> P0, D -> P1 (out-proj split-K fp32 partials).
    bf16* xb     = (bf16*)d_ws;
    bf16* ebuf   = xb;
    bf16* WT_qkv = xb + (size_t)4 * 1024 * 1024;
    bf16* WT_out = WT_qkv + (size_t)8 * 1024 * 1024;
    bf16* qkvb   = WT_out + (size_t)4 * 1024 * 1024;
    bf16* Op0    = (bf16*)d_out;                         // attn O-partial z=0
    bf16* Op1    = (bf16*)d_out + (size_t)4 * 1024 * 1024;  // attn O-partial z=1
    float* Lp    = (float*)WT_qkv;                       // attn l-partials (256KB)
    float* P0    = (float*)WT_qkv;
    float* P1    = (float*)qkvb;
    float* outp  = (float*)d_out;

    prep_k<<<dim3(14336), dim3(256), 0, stream>>>(x, qk, kvk, ok, xb, WT_qkv, WT_out);
    gemm_qkv_3buf_k<<<dim3(256), dim3(512), 0, stream>>>(xb, WT_qkv, qkvb);
    rope_kk<<<dim3(T_DIM), dim3(256), 0, stream>>>(qkvb, segp);
    attn_k<<<dim3(512), dim3(512), 0, stream>>>(qkvb, segp, Op0, Op1, Lp);
    attn_comb_k<<<dim3(T_DIM), dim3(256), 0, stream>>>(Op0, Op1, Lp, ebuf);
    mfma_gemm_splitk_k<<<dim3(16, 16, 2), dim3(256), 0, stream>>>(
        ebuf, WT_out, P0, P1);
    add_out_k<<<dim3(4096), dim3(256), 0, stream>>>(P0, P1, outp);
}